// Round 4
// baseline (867.219 us; speedup 1.0000x reference)
//
#include <hip/hip_runtime.h>
#include <cstdint>
#include <cstddef>

#define CCH 128
#define BCAP 2048   // coarse-bucket capacity (mean ~1024, >30 sigma headroom)

typedef __attribute__((ext_vector_type(8))) short short8;
typedef __attribute__((ext_vector_type(4))) float floatx4;

__device__ __forceinline__ unsigned short f2bf(float f) {
    unsigned u = __builtin_bit_cast(unsigned, f);
    u += 0x7fffu + ((u >> 16) & 1u);   // RNE
    return (unsigned short)(u >> 16);
}
__device__ __forceinline__ float bf2f(unsigned short h) {
    unsigned u = ((unsigned)h) << 16;
    return __builtin_bit_cast(float, u);
}
__device__ __forceinline__ float sigmoidf_(float x) { return 1.0f / (1.0f + __expf(-x)); }

// ---------------- weight prep: fragment-ready bf16 ----------------
// W_ih frag layout: [rel][g(3)][ct(8)][kc(4)][lane(64)][j(8)]; gates {i,g,o} -> rows {0,256,384}
__global__ __launch_bounds__(256) void prep_wih_kernel(
    const float* __restrict__ W0, const float* __restrict__ W1,
    unsigned short* __restrict__ frag)
{
    int t = blockIdx.x * 256 + threadIdx.x;           // 2*3*8*4*64 = 12288
    if (t >= 12288) return;
    int l  = t & 63;
    int kc = (t >> 6) & 3;
    int ct = (t >> 8) & 7;
    int g  = (t >> 11) % 3;
    int rel = t / 6144;
    int gb = (g == 0) ? 0 : (g == 1 ? 256 : 384);
    const float* W = rel ? W1 : W0;
    int n  = gb + ct * 16 + (l & 15);
    int kb = kc * 32 + (l >> 4) * 8;
    unsigned short* o = frag + (size_t)t * 8;
#pragma unroll
    for (int j = 0; j < 8; j++) o[j] = f2bf(W[(size_t)n * CCH + kb + j]);
}

// W_lin frag layout: [rel][ct(8)][kc(8)][lane(64)][j(8)]; W_lin is [128][256]
__global__ __launch_bounds__(256) void prep_wlin_kernel(
    const float* __restrict__ W0, const float* __restrict__ W1,
    unsigned short* __restrict__ frag)
{
    int t = blockIdx.x * 256 + threadIdx.x;           // 2*8*8*64 = 8192
    if (t >= 8192) return;
    int l  = t & 63;
    int kc = (t >> 6) & 7;
    int ct = (t >> 9) & 7;
    int rel = t >> 12;
    const float* W = rel ? W1 : W0;
    int n  = ct * 16 + (l & 15);
    int kb = kc * 32 + (l >> 4) * 8;
    unsigned short* o = frag + (size_t)t * 8;
#pragma unroll
    for (int j = 0; j < 8; j++) o[j] = f2bf(W[(size_t)n * 256 + kb + j]);
}

// ---------------- LSTM message via MFMA ----------------
#define XPAD 136
__global__ __launch_bounds__(256) void lstm_mfma_kernel(
    const float* __restrict__ x0, const float* __restrict__ x1,
    const unsigned short* __restrict__ wfrag,
    const float* __restrict__ b0, const float* __restrict__ b1,
    unsigned short* __restrict__ msg0, unsigned short* __restrict__ msg1,
    int N0, int N1, int nblk0)
{
    __shared__ unsigned short xs[32 * XPAD];
    const int rel = (blockIdx.x >= nblk0);
    const int nb = (rel ? (blockIdx.x - nblk0) : blockIdx.x) * 32;
    const float* x = rel ? x1 : x0;
    const float* bias = rel ? b1 : b0;
    unsigned short* msg = rel ? msg1 : msg0;
    const int N = rel ? N1 : N0;
    const unsigned short* wf = wfrag + (size_t)rel * 6144 * 8;

    {
        int t = threadIdx.x;
        int r = t >> 3;
        int c0 = (t & 7) * 16;
        int n = nb + r;
        unsigned short* dstp = xs + r * XPAD + c0;
        if (n < N) {
            const float4* srcp = (const float4*)(x + (size_t)n * CCH + c0);
#pragma unroll
            for (int qq = 0; qq < 4; qq++) {
                float4 v = srcp[qq];
                unsigned u0 = (unsigned)f2bf(v.x) | ((unsigned)f2bf(v.y) << 16);
                unsigned u1 = (unsigned)f2bf(v.z) | ((unsigned)f2bf(v.w) << 16);
                *(uint2*)(dstp + qq * 4) = make_uint2(u0, u1);
            }
        } else {
#pragma unroll
            for (int qq = 0; qq < 4; qq++) *(uint2*)(dstp + qq * 4) = make_uint2(0u, 0u);
        }
    }
    __syncthreads();

    const int tid = threadIdx.x;
    const int w = tid >> 6;
    const int l = tid & 63;
    const int mt = w & 1;
    const int ctb = (w >> 1) * 4;
    const int q = l >> 4;
    const int m16 = l & 15;

    floatx4 acc[3][4];
#pragma unroll
    for (int g = 0; g < 3; g++)
#pragma unroll
        for (int c = 0; c < 4; c++) acc[g][c] = (floatx4){0.f, 0.f, 0.f, 0.f};

    const unsigned short* arow = xs + (mt * 16 + m16) * XPAD + q * 8;
#pragma unroll
    for (int kc = 0; kc < 4; kc++) {
        short8 af = *(const short8*)(arow + kc * 32);
#pragma unroll
        for (int g = 0; g < 3; g++)
#pragma unroll
            for (int c = 0; c < 4; c++) {
                const unsigned short* bp = wf + ((((size_t)g * 8 + (ctb + c)) * 4 + kc) * 64 + l) * 8;
                short8 bv = *(const short8*)bp;
                acc[g][c] = __builtin_amdgcn_mfma_f32_16x16x32_bf16(af, bv, acc[g][c], 0, 0, 0);
            }
    }

#pragma unroll
    for (int c = 0; c < 4; c++) {
        const int col = (ctb + c) * 16 + m16;
        const float bi = bias[col], bg = bias[256 + col], bo = bias[384 + col];
#pragma unroll
        for (int r = 0; r < 4; r++) {
            const int node = nb + mt * 16 + q * 4 + r;
            if (node < N) {
                float iv = sigmoidf_(acc[0][c][r] + bi);
                float gv = tanhf(acc[1][c][r] + bg);
                float ov = sigmoidf_(acc[2][c][r] + bo);
                msg[(size_t)node * CCH + col] = f2bf(ov * tanhf(iv * gv));
            }
        }
    }
}

// ---------------- coarse histogram over dst>>6 buckets ----------------
__global__ __launch_bounds__(256) void coarse_hist_kernel(
    const int* __restrict__ dst0, const int* __restrict__ dst1,
    int* __restrict__ cdeg, int E0, int E1, int nb0)
{
    int e = blockIdx.x * 256 + threadIdx.x;
    if (e < E0) atomicAdd(&cdeg[dst0[e] >> 6], 1);
    else if (e < E0 + E1) atomicAdd(&cdeg[nb0 + (dst1[e - E0] >> 6)], 1);
}

// single block: exclusive scan over NBK bucket counts -> coff, ccur
__global__ __launch_bounds__(256) void coarse_scan_kernel(
    const int* __restrict__ cdeg, int* __restrict__ coff, int* __restrict__ ccur, int NBK)
{
    __shared__ int s[256];
    __shared__ int carry;
    const int tid = threadIdx.x;
    if (tid == 0) carry = 0;
    __syncthreads();
    for (int base = 0; base < NBK; base += 256) {
        int i = base + tid;
        int v = (i < NBK) ? cdeg[i] : 0;
        s[tid] = v;
        __syncthreads();
#pragma unroll
        for (int off = 1; off < 256; off <<= 1) {
            int t = (tid >= off) ? s[tid - off] : 0;
            __syncthreads();
            s[tid] += t;
            __syncthreads();
        }
        int excl = s[tid] - v + carry;
        if (i < NBK) { coff[i] = excl; ccur[i] = excl; }
        __syncthreads();
        if (tid == 255) carry += s[255];
        __syncthreads();
    }
}

// scatter packed (dst&63)<<26 | src into coarse buckets (1564 active streams -> L2-friendly)
__global__ __launch_bounds__(256) void bucket_scatter_kernel(
    const int* __restrict__ src0, const int* __restrict__ dst0,
    const int* __restrict__ src1, const int* __restrict__ dst1,
    int* __restrict__ ccur, unsigned* __restrict__ packed, int E0, int E1, int nb0)
{
    int e = blockIdx.x * 256 + threadIdx.x;
    int s, d, g;
    if (e < E0)           { s = src0[e]; d = dst0[e]; g = d >> 6; }
    else if (e < E0 + E1) { int ee = e - E0; s = src1[ee]; d = dst1[ee]; g = nb0 + (d >> 6); }
    else return;
    int p = atomicAdd(&ccur[g], 1);
    packed[p] = ((unsigned)(d & 63) << 26) | (unsigned)s;
}

// one block per bucket: in-LDS counting sort by 6-bit key; write sorted src back in place
// (sequential), emit deg/offs (absolute into csr) for the bucket's 64 dst nodes.
__global__ __launch_bounds__(256) void bucket_sort_kernel(
    unsigned* __restrict__ packed, const int* __restrict__ coff, const int* __restrict__ cdeg,
    int* __restrict__ offs0, int* __restrict__ deg0,
    int* __restrict__ offs1, int* __restrict__ deg1,
    int N0, int N1, int nb0)
{
    __shared__ unsigned pin[BCAP];
    __shared__ int ssrc[BCAP];
    __shared__ int lhist[64], lscan[64], lcur[64];
    const int tid = threadIdx.x;
    const int g = blockIdx.x;
    const int base = coff[g];
    const int cnt = min(cdeg[g], BCAP);

    for (int i = tid; i < cnt; i += 256) pin[i] = packed[base + i];
    if (tid < 64) lhist[tid] = 0;
    __syncthreads();
    for (int i = tid; i < cnt; i += 256) atomicAdd(&lhist[pin[i] >> 26], 1);
    __syncthreads();
    if (tid < 64) lscan[tid] = lhist[tid];
    __syncthreads();
#pragma unroll
    for (int off = 1; off < 64; off <<= 1) {
        int t = (tid < 64 && tid >= off) ? lscan[tid - off] : 0;
        __syncthreads();
        if (tid < 64) lscan[tid] += t;
        __syncthreads();
    }
    if (tid < 64) {
        int excl = lscan[tid] - lhist[tid];
        lcur[tid] = excl;
        const int rel = (g >= nb0);
        const int lb = rel ? g - nb0 : g;
        const int n = lb * 64 + tid;
        const int N = rel ? N1 : N0;
        if (n < N) {
            if (rel) { offs1[n] = base + excl; deg1[n] = lhist[tid]; }
            else     { offs0[n] = base + excl; deg0[n] = lhist[tid]; }
        }
    }
    __syncthreads();
    for (int i = tid; i < cnt; i += 256) {
        unsigned p = pin[i];
        int pos = atomicAdd(&lcur[p >> 26], 1);
        ssrc[pos] = (int)(p & 0x03FFFFFFu);
    }
    __syncthreads();
    for (int i = tid; i < cnt; i += 256) ((int*)packed)[base + i] = ssrc[i];
}

// ---------------- gather: one wave per dst node, bf16 msg ----------------
__global__ __launch_bounds__(256) void gather_kernel(
    const unsigned short* __restrict__ msg0, const unsigned short* __restrict__ msg1,
    const int* __restrict__ csr,
    const int* __restrict__ offs0, const int* __restrict__ offs1,
    const int* __restrict__ deg0, const int* __restrict__ deg1,
    unsigned short* __restrict__ aggr0, unsigned short* __restrict__ aggr1,
    int N0, int N1)
{
    const int wv = blockIdx.x * 4 + (threadIdx.x >> 6);
    const int l = threadIdx.x & 63;
    const unsigned short* msg; unsigned short* aggr;
    int n, start, cnt;
    if (wv < N0)            { n = wv;      msg = msg0; start = offs0[n]; cnt = deg0[n]; aggr = aggr0; }
    else if (wv < N0 + N1)  { n = wv - N0; msg = msg1; start = offs1[n]; cnt = deg1[n]; aggr = aggr1; }
    else return;

    float ax = 0.f, ay = 0.f;
    const int* ce = csr + start;
    const unsigned short* mb = msg + l * 2;
    int j = 0;
    for (; j + 4 <= cnt; j += 4) {
        int s0 = ce[j], s1 = ce[j + 1], s2 = ce[j + 2], s3 = ce[j + 3];
        unsigned u0 = *(const unsigned*)(mb + (size_t)s0 * CCH);
        unsigned u1 = *(const unsigned*)(mb + (size_t)s1 * CCH);
        unsigned u2 = *(const unsigned*)(mb + (size_t)s2 * CCH);
        unsigned u3 = *(const unsigned*)(mb + (size_t)s3 * CCH);
        ax += bf2f((unsigned short)u0) + bf2f((unsigned short)u1)
            + bf2f((unsigned short)u2) + bf2f((unsigned short)u3);
        ay += bf2f((unsigned short)(u0 >> 16)) + bf2f((unsigned short)(u1 >> 16))
            + bf2f((unsigned short)(u2 >> 16)) + bf2f((unsigned short)(u3 >> 16));
    }
    for (; j < cnt; j++) {
        unsigned u0 = *(const unsigned*)(mb + (size_t)ce[j] * CCH);
        ax += bf2f((unsigned short)u0);
        ay += bf2f((unsigned short)(u0 >> 16));
    }
    unsigned o = (unsigned)f2bf(ax) | ((unsigned)f2bf(ay) << 16);
    *(unsigned*)(aggr + (size_t)n * CCH + l * 2) = o;
}

// ---------------- final linear via MFMA ----------------
#define APAD 264
__global__ __launch_bounds__(256) void linear_mfma_kernel(
    const float* __restrict__ xd0, const float* __restrict__ xd1,
    const unsigned short* __restrict__ ag0, const unsigned short* __restrict__ ag1,
    const unsigned short* __restrict__ wfrag,
    const float* __restrict__ bl0, const float* __restrict__ bl1,
    float* __restrict__ out0, float* __restrict__ out1,
    int N0, int N1, int nblk0)
{
    __shared__ unsigned short s[32 * APAD];
    const int rel = (blockIdx.x >= nblk0);
    const int nb = (rel ? blockIdx.x - nblk0 : blockIdx.x) * 32;
    const float* xd = rel ? xd1 : xd0;
    const unsigned short* ag = rel ? ag1 : ag0;
    const float* bl = rel ? bl1 : bl0;
    float* outp = rel ? out1 : out0;
    const int N = rel ? N1 : N0;
    const unsigned short* wf = wfrag + (size_t)rel * 4096 * 8;

    {
        int t = threadIdx.x;
        int r = t >> 3;
        int c0 = (t & 7) * 16;
        int n = nb + r;
        unsigned short* drow = s + r * APAD;
        if (n < N) {
            const float4* srcp = (const float4*)(xd + (size_t)n * CCH + c0);
#pragma unroll
            for (int qq = 0; qq < 4; qq++) {
                float4 v = srcp[qq];
                unsigned u0 = (unsigned)f2bf(v.x) | ((unsigned)f2bf(v.y) << 16);
                unsigned u1 = (unsigned)f2bf(v.z) | ((unsigned)f2bf(v.w) << 16);
                *(uint2*)(drow + c0 + qq * 4) = make_uint2(u0, u1);
            }
            const uint4* ap = (const uint4*)(ag + (size_t)n * CCH + c0);
            *(uint4*)(drow + CCH + c0) = ap[0];
            *(uint4*)(drow + CCH + c0 + 8) = ap[1];
        } else {
            uint4 z = make_uint4(0u, 0u, 0u, 0u);
            *(uint4*)(drow + c0) = z;
            *(uint4*)(drow + c0 + 8) = z;
            *(uint4*)(drow + CCH + c0) = z;
            *(uint4*)(drow + CCH + c0 + 8) = z;
        }
    }
    __syncthreads();

    const int tid = threadIdx.x;
    const int w = tid >> 6;
    const int l = tid & 63;
    const int mt = w & 1;
    const int ctb = (w >> 1) * 4;
    const int q = l >> 4;
    const int m16 = l & 15;

    floatx4 acc[4];
#pragma unroll
    for (int c = 0; c < 4; c++) acc[c] = (floatx4){0.f, 0.f, 0.f, 0.f};

    const unsigned short* arow = s + (mt * 16 + m16) * APAD + q * 8;
#pragma unroll
    for (int kc = 0; kc < 8; kc++) {
        short8 af = *(const short8*)(arow + kc * 32);
#pragma unroll
        for (int c = 0; c < 4; c++) {
            const unsigned short* bp = wf + ((((size_t)(ctb + c)) * 8 + kc) * 64 + l) * 8;
            short8 bv = *(const short8*)bp;
            acc[c] = __builtin_amdgcn_mfma_f32_16x16x32_bf16(af, bv, acc[c], 0, 0, 0);
        }
    }

#pragma unroll
    for (int c = 0; c < 4; c++) {
        const int col = (ctb + c) * 16 + m16;
        const float bv = bl[col];
#pragma unroll
        for (int r = 0; r < 4; r++) {
            const int node = nb + mt * 16 + q * 4 + r;
            if (node < N) outp[(size_t)node * CCH + col] = fmaxf(acc[c][r] + bv, 0.0f);
        }
    }
}

extern "C" void kernel_launch(void* const* d_in, const int* in_sizes, int n_in,
                              void* d_out, int out_size, void* d_ws, size_t ws_size,
                              hipStream_t stream) {
    const float* x_a      = (const float*)d_in[0];
    const float* x_b      = (const float*)d_in[1];
    const int*   e_ab     = (const int*)d_in[2];
    const int*   e_ba     = (const int*)d_in[3];
    const float* W_ih_ab  = (const float*)d_in[4];
    const float* b_ab     = (const float*)d_in[5];
    const float* W_lin_ab = (const float*)d_in[6];
    const float* b_lin_ab = (const float*)d_in[7];
    const float* W_ih_ba  = (const float*)d_in[8];
    const float* b_ba     = (const float*)d_in[9];
    const float* W_lin_ba = (const float*)d_in[10];
    const float* b_lin_ba = (const float*)d_in[11];

    const int NA = in_sizes[0] / CCH;
    const int NB = in_sizes[1] / CCH;
    const int E0 = in_sizes[2] / 2;   // a->b (dst in B)
    const int E1 = in_sizes[3] / 2;   // b->a (dst in A)

    float* out = (float*)d_out;
    char* ws = (char*)d_ws;
    size_t off = 0;
    auto alloc = [&](size_t bytes) { char* p = ws + off; off += (bytes + 255) & ~(size_t)255; return p; };

    unsigned short* wfrag_ih  = (unsigned short*)alloc(12288 * 8 * 2);
    unsigned short* wfrag_lin = (unsigned short*)alloc(8192 * 8 * 2);
    unsigned short* msg_a     = (unsigned short*)alloc((size_t)NA * CCH * 2);
    unsigned short* msg_b     = (unsigned short*)alloc((size_t)NB * CCH * 2);
    unsigned short* aggr_b    = (unsigned short*)alloc((size_t)NB * CCH * 2);
    unsigned short* aggr_a    = (unsigned short*)alloc((size_t)NA * CCH * 2);

    const int nb0 = (NB + 63) / 64;   // coarse buckets rel0 (dst in B)
    const int nb1 = (NA + 63) / 64;   // rel1 (dst in A)
    const int NBK = nb0 + nb1;

    int* cdeg   = (int*)alloc((size_t)NBK * 4);
    int* coff   = (int*)alloc((size_t)NBK * 4);
    int* ccur   = (int*)alloc((size_t)NBK * 4);
    int* offs_b = (int*)alloc((size_t)NB * 4);
    int* offs_a = (int*)alloc((size_t)NA * 4);
    int* deg_b  = (int*)alloc((size_t)NB * 4);
    int* deg_a  = (int*)alloc((size_t)NA * 4);
    unsigned* packed = (unsigned*)alloc((size_t)(E0 + E1) * 4);  // becomes csr after sort

    const int nblkA = (NA + 31) / 32;
    const int nblkB = (NB + 31) / 32;

    hipMemsetAsync(cdeg, 0, (size_t)NBK * 4, stream);

    prep_wih_kernel<<<48, 256, 0, stream>>>(W_ih_ab, W_ih_ba, wfrag_ih);
    prep_wlin_kernel<<<32, 256, 0, stream>>>(W_lin_ab, W_lin_ba, wfrag_lin);

    // rel0: a->b (src A, msg_a); rel1: b->a (src B, msg_b)
    lstm_mfma_kernel<<<nblkA + nblkB, 256, 0, stream>>>(
        x_a, x_b, wfrag_ih, b_ab, b_ba, msg_a, msg_b, NA, NB, nblkA);

    coarse_hist_kernel<<<(E0 + E1 + 255) / 256, 256, 0, stream>>>(
        e_ab + E0, e_ba + E1, cdeg, E0, E1, nb0);
    coarse_scan_kernel<<<1, 256, 0, stream>>>(cdeg, coff, ccur, NBK);
    bucket_scatter_kernel<<<(E0 + E1 + 255) / 256, 256, 0, stream>>>(
        e_ab, e_ab + E0, e_ba, e_ba + E1, ccur, packed, E0, E1, nb0);
    bucket_sort_kernel<<<NBK, 256, 0, stream>>>(
        packed, coff, cdeg, offs_b, deg_b, offs_a, deg_a, NB, NA, nb0);

    gather_kernel<<<(NB + NA + 3) / 4, 256, 0, stream>>>(
        msg_a, msg_b, (const int*)packed, offs_b, offs_a, deg_b, deg_a, aggr_b, aggr_a, NB, NA);

    // rel0 output -> out_b (index 1), rel1 -> out_a (index 0)
    linear_mfma_kernel<<<nblkB + nblkA, 256, 0, stream>>>(
        x_b, x_a, aggr_b, aggr_a, wfrag_lin, b_lin_ab, b_lin_ba,
        out + (size_t)NA * CCH, out, NB, NA, nblkB);
}

// Round 5
// 323.330 us; speedup vs baseline: 2.6821x; 2.6821x over previous
//
#include <hip/hip_runtime.h>
#include <cstdint>
#include <cstddef>

#define CCH 128
#define TK 8192      // edges per tile in CSR build
#define FCAP 8192    // fine-sort bucket capacity (mean ~4096, sigma ~64)
#define MAXBKT 512   // max coarse buckets (392 actual)

typedef __attribute__((ext_vector_type(8))) short short8;
typedef __attribute__((ext_vector_type(4))) float floatx4;

__device__ __forceinline__ unsigned short f2bf(float f) {
    unsigned u = __builtin_bit_cast(unsigned, f);
    u += 0x7fffu + ((u >> 16) & 1u);   // RNE
    return (unsigned short)(u >> 16);
}
__device__ __forceinline__ float bf2f(unsigned short h) {
    unsigned u = ((unsigned)h) << 16;
    return __builtin_bit_cast(float, u);
}
__device__ __forceinline__ float sigmoidf_(float x) { return 1.0f / (1.0f + __expf(-x)); }

// ---------------- weight prep: fragment-ready bf16 ----------------
__global__ __launch_bounds__(256) void prep_wih_kernel(
    const float* __restrict__ W0, const float* __restrict__ W1,
    unsigned short* __restrict__ frag)
{
    int t = blockIdx.x * 256 + threadIdx.x;           // 2*3*8*4*64 = 12288
    if (t >= 12288) return;
    int l  = t & 63;
    int kc = (t >> 6) & 3;
    int ct = (t >> 8) & 7;
    int g  = (t >> 11) % 3;
    int rel = t / 6144;
    int gb = (g == 0) ? 0 : (g == 1 ? 256 : 384);
    const float* W = rel ? W1 : W0;
    int n  = gb + ct * 16 + (l & 15);
    int kb = kc * 32 + (l >> 4) * 8;
    unsigned short* o = frag + (size_t)t * 8;
#pragma unroll
    for (int j = 0; j < 8; j++) o[j] = f2bf(W[(size_t)n * CCH + kb + j]);
}

__global__ __launch_bounds__(256) void prep_wlin_kernel(
    const float* __restrict__ W0, const float* __restrict__ W1,
    unsigned short* __restrict__ frag)
{
    int t = blockIdx.x * 256 + threadIdx.x;           // 2*8*8*64 = 8192
    if (t >= 8192) return;
    int l  = t & 63;
    int kc = (t >> 6) & 7;
    int ct = (t >> 9) & 7;
    int rel = t >> 12;
    const float* W = rel ? W1 : W0;
    int n  = ct * 16 + (l & 15);
    int kb = kc * 32 + (l >> 4) * 8;
    unsigned short* o = frag + (size_t)t * 8;
#pragma unroll
    for (int j = 0; j < 8; j++) o[j] = f2bf(W[(size_t)n * 256 + kb + j]);
}

// ---------------- LSTM message via MFMA ----------------
#define XPAD 136
__global__ __launch_bounds__(256) void lstm_mfma_kernel(
    const float* __restrict__ x0, const float* __restrict__ x1,
    const unsigned short* __restrict__ wfrag,
    const float* __restrict__ b0, const float* __restrict__ b1,
    unsigned short* __restrict__ msg0, unsigned short* __restrict__ msg1,
    int N0, int N1, int nblk0)
{
    __shared__ unsigned short xs[32 * XPAD];
    const int rel = (blockIdx.x >= nblk0);
    const int nb = (rel ? (blockIdx.x - nblk0) : blockIdx.x) * 32;
    const float* x = rel ? x1 : x0;
    const float* bias = rel ? b1 : b0;
    unsigned short* msg = rel ? msg1 : msg0;
    const int N = rel ? N1 : N0;
    const unsigned short* wf = wfrag + (size_t)rel * 6144 * 8;

    {
        int t = threadIdx.x;
        int r = t >> 3;
        int c0 = (t & 7) * 16;
        int n = nb + r;
        unsigned short* dstp = xs + r * XPAD + c0;
        if (n < N) {
            const float4* srcp = (const float4*)(x + (size_t)n * CCH + c0);
#pragma unroll
            for (int qq = 0; qq < 4; qq++) {
                float4 v = srcp[qq];
                unsigned u0 = (unsigned)f2bf(v.x) | ((unsigned)f2bf(v.y) << 16);
                unsigned u1 = (unsigned)f2bf(v.z) | ((unsigned)f2bf(v.w) << 16);
                *(uint2*)(dstp + qq * 4) = make_uint2(u0, u1);
            }
        } else {
#pragma unroll
            for (int qq = 0; qq < 4; qq++) *(uint2*)(dstp + qq * 4) = make_uint2(0u, 0u);
        }
    }
    __syncthreads();

    const int tid = threadIdx.x;
    const int w = tid >> 6;
    const int l = tid & 63;
    const int mt = w & 1;
    const int ctb = (w >> 1) * 4;
    const int q = l >> 4;
    const int m16 = l & 15;

    floatx4 acc[3][4];
#pragma unroll
    for (int g = 0; g < 3; g++)
#pragma unroll
        for (int c = 0; c < 4; c++) acc[g][c] = (floatx4){0.f, 0.f, 0.f, 0.f};

    const unsigned short* arow = xs + (mt * 16 + m16) * XPAD + q * 8;
#pragma unroll
    for (int kc = 0; kc < 4; kc++) {
        short8 af = *(const short8*)(arow + kc * 32);
#pragma unroll
        for (int g = 0; g < 3; g++)
#pragma unroll
            for (int c = 0; c < 4; c++) {
                const unsigned short* bp = wf + ((((size_t)g * 8 + (ctb + c)) * 4 + kc) * 64 + l) * 8;
                short8 bv = *(const short8*)bp;
                acc[g][c] = __builtin_amdgcn_mfma_f32_16x16x32_bf16(af, bv, acc[g][c], 0, 0, 0);
            }
    }

#pragma unroll
    for (int c = 0; c < 4; c++) {
        const int col = (ctb + c) * 16 + m16;
        const float bi = bias[col], bg = bias[256 + col], bo = bias[384 + col];
#pragma unroll
        for (int r = 0; r < 4; r++) {
            const int node = nb + mt * 16 + q * 4 + r;
            if (node < N) {
                float iv = sigmoidf_(acc[0][c][r] + bi);
                float gv = tanhf(acc[1][c][r] + bg);
                float ov = sigmoidf_(acc[2][c][r] + bo);
                msg[(size_t)node * CCH + col] = f2bf(ov * tanhf(iv * gv));
            }
        }
    }
}

// ---------------- CSR build: zero global atomics ----------------
// Pass 1: per-tile LDS histogram over coarse buckets (dst>>8), write H row plainly.
__global__ __launch_bounds__(256) void tile_hist_kernel(
    const int* __restrict__ dst0, const int* __restrict__ dst1,
    int* __restrict__ H, int E0, int E1, int nbkt0, int NBKT)
{
    __shared__ int h[MAXBKT];
    const int tid = threadIdx.x;
    for (int i = tid; i < NBKT; i += 256) h[i] = 0;
    __syncthreads();
    const long long Etot = (long long)E0 + E1;
    const long long base = (long long)blockIdx.x * TK;
    for (int i = tid; i < TK; i += 256) {
        long long e = base + i;
        if (e >= Etot) break;
        int g;
        if (e < E0) g = dst0[e] >> 8;
        else        g = nbkt0 + (dst1[e - E0] >> 8);
        atomicAdd(&h[g], 1);
    }
    __syncthreads();
    int* row = H + (size_t)blockIdx.x * NBKT;
    for (int i = tid; i < NBKT; i += 256) row[i] = h[i];
}

// Pass 2a: per-bucket exclusive scan over tiles (in place), bucket totals out.
__global__ __launch_bounds__(256) void colscan_kernel(
    int* __restrict__ H, int* __restrict__ btot, int nT, int NBKT)
{
    __shared__ int s[256];
    __shared__ int carry;
    const int g = blockIdx.x;
    const int tid = threadIdx.x;
    if (tid == 0) carry = 0;
    __syncthreads();
    for (int base = 0; base < nT; base += 256) {
        int b = base + tid;
        int v = (b < nT) ? H[(size_t)b * NBKT + g] : 0;
        s[tid] = v;
        __syncthreads();
#pragma unroll
        for (int off = 1; off < 256; off <<= 1) {
            int t = (tid >= off) ? s[tid - off] : 0;
            __syncthreads();
            s[tid] += t;
            __syncthreads();
        }
        if (b < nT) H[(size_t)b * NBKT + g] = s[tid] - v + carry;
        __syncthreads();
        if (tid == 255) carry += s[255];
        __syncthreads();
    }
    if (tid == 0) btot[g] = carry;
}

// Pass 2b: single-block exclusive scan of bucket totals -> coff.
__global__ __launch_bounds__(256) void scanb_kernel(
    const int* __restrict__ btot, int* __restrict__ coff, int NBKT)
{
    __shared__ int s[256];
    __shared__ int carry;
    const int tid = threadIdx.x;
    if (tid == 0) carry = 0;
    __syncthreads();
    for (int base = 0; base < NBKT; base += 256) {
        int i = base + tid;
        int v = (i < NBKT) ? btot[i] : 0;
        s[tid] = v;
        __syncthreads();
#pragma unroll
        for (int off = 1; off < 256; off <<= 1) {
            int t = (tid >= off) ? s[tid - off] : 0;
            __syncthreads();
            s[tid] += t;
            __syncthreads();
        }
        if (i < NBKT) coff[i] = s[tid] - v + carry;
        __syncthreads();
        if (tid == 255) carry += s[255];
        __syncthreads();
    }
}

// Pass 3: re-read edges; LDS cursors = coff[g]+H[tile][g]; write packed (dst&255)<<24|src.
__global__ __launch_bounds__(256) void tile_scatter_kernel(
    const int* __restrict__ src0, const int* __restrict__ dst0,
    const int* __restrict__ src1, const int* __restrict__ dst1,
    const int* __restrict__ H, const int* __restrict__ coff,
    unsigned* __restrict__ packed, int E0, int E1, int nbkt0, int NBKT)
{
    __shared__ int cur[MAXBKT];
    const int tid = threadIdx.x;
    const int* row = H + (size_t)blockIdx.x * NBKT;
    for (int i = tid; i < NBKT; i += 256) cur[i] = coff[i] + row[i];
    __syncthreads();
    const long long Etot = (long long)E0 + E1;
    const long long base = (long long)blockIdx.x * TK;
    for (int i = tid; i < TK; i += 256) {
        long long e = base + i;
        if (e >= Etot) break;
        int s, g, k;
        if (e < E0) { int d = dst0[e]; s = src0[e]; g = d >> 8; k = d & 255; }
        else { long long ee = e - E0; int d = dst1[ee]; s = src1[ee]; g = nbkt0 + (d >> 8); k = d & 255; }
        int pos = atomicAdd(&cur[g], 1);
        packed[pos] = ((unsigned)k << 24) | (unsigned)s;
    }
}

// Pass 4: one block per bucket; in-LDS counting sort by 8-bit key; emit deg/offs.
__global__ __launch_bounds__(256) void fine_sort_kernel(
    unsigned* __restrict__ packed, const int* __restrict__ coff, const int* __restrict__ btot,
    int* __restrict__ offs0, int* __restrict__ deg0,
    int* __restrict__ offs1, int* __restrict__ deg1,
    int N0, int N1, int nbkt0)
{
    __shared__ unsigned pin[FCAP];
    __shared__ int sout[FCAP];
    __shared__ int hist[256], scn[256], cur[256];
    const int g = blockIdx.x;
    const int tid = threadIdx.x;
    const int base = coff[g];
    const int cnt = min(btot[g], FCAP);

    for (int i = tid; i < cnt; i += 256) pin[i] = packed[base + i];
    hist[tid] = 0;
    __syncthreads();
    for (int i = tid; i < cnt; i += 256) atomicAdd(&hist[pin[i] >> 24], 1);
    __syncthreads();
    int v = hist[tid];
    scn[tid] = v;
    __syncthreads();
#pragma unroll
    for (int off = 1; off < 256; off <<= 1) {
        int t = (tid >= off) ? scn[tid - off] : 0;
        __syncthreads();
        scn[tid] += t;
        __syncthreads();
    }
    int excl = scn[tid] - v;
    cur[tid] = excl;
    {
        const int rel = (g >= nbkt0);
        const int lb = rel ? g - nbkt0 : g;
        const int n = lb * 256 + tid;
        const int N = rel ? N1 : N0;
        if (n < N) {
            if (rel) { offs1[n] = base + excl; deg1[n] = v; }
            else     { offs0[n] = base + excl; deg0[n] = v; }
        }
    }
    __syncthreads();
    for (int i = tid; i < cnt; i += 256) {
        unsigned p = pin[i];
        int pos = atomicAdd(&cur[p >> 24], 1);
        sout[pos] = (int)(p & 0x00FFFFFFu);
    }
    __syncthreads();
    int* op = (int*)packed;
    for (int i = tid; i < cnt; i += 256) op[base + i] = sout[i];
}

// ---------------- gather: one wave per dst node, bf16 msg ----------------
__global__ __launch_bounds__(256) void gather_kernel(
    const unsigned short* __restrict__ msg0, const unsigned short* __restrict__ msg1,
    const int* __restrict__ csr,
    const int* __restrict__ offs0, const int* __restrict__ offs1,
    const int* __restrict__ deg0, const int* __restrict__ deg1,
    unsigned short* __restrict__ aggr0, unsigned short* __restrict__ aggr1,
    int N0, int N1)
{
    const int wv = blockIdx.x * 4 + (threadIdx.x >> 6);
    const int l = threadIdx.x & 63;
    const unsigned short* msg; unsigned short* aggr;
    int n, start, cnt;
    if (wv < N0)            { n = wv;      msg = msg0; start = offs0[n]; cnt = deg0[n]; aggr = aggr0; }
    else if (wv < N0 + N1)  { n = wv - N0; msg = msg1; start = offs1[n]; cnt = deg1[n]; aggr = aggr1; }
    else return;

    float ax = 0.f, ay = 0.f;
    const int* ce = csr + start;
    const unsigned short* mb = msg + l * 2;
    int j = 0;
    for (; j + 4 <= cnt; j += 4) {
        int s0 = ce[j], s1 = ce[j + 1], s2 = ce[j + 2], s3 = ce[j + 3];
        unsigned u0 = *(const unsigned*)(mb + (size_t)s0 * CCH);
        unsigned u1 = *(const unsigned*)(mb + (size_t)s1 * CCH);
        unsigned u2 = *(const unsigned*)(mb + (size_t)s2 * CCH);
        unsigned u3 = *(const unsigned*)(mb + (size_t)s3 * CCH);
        ax += bf2f((unsigned short)u0) + bf2f((unsigned short)u1)
            + bf2f((unsigned short)u2) + bf2f((unsigned short)u3);
        ay += bf2f((unsigned short)(u0 >> 16)) + bf2f((unsigned short)(u1 >> 16))
            + bf2f((unsigned short)(u2 >> 16)) + bf2f((unsigned short)(u3 >> 16));
    }
    for (; j < cnt; j++) {
        unsigned u0 = *(const unsigned*)(mb + (size_t)ce[j] * CCH);
        ax += bf2f((unsigned short)u0);
        ay += bf2f((unsigned short)(u0 >> 16));
    }
    unsigned o = (unsigned)f2bf(ax) | ((unsigned)f2bf(ay) << 16);
    *(unsigned*)(aggr + (size_t)n * CCH + l * 2) = o;
}

// ---------------- final linear via MFMA ----------------
#define APAD 264
__global__ __launch_bounds__(256) void linear_mfma_kernel(
    const float* __restrict__ xd0, const float* __restrict__ xd1,
    const unsigned short* __restrict__ ag0, const unsigned short* __restrict__ ag1,
    const unsigned short* __restrict__ wfrag,
    const float* __restrict__ bl0, const float* __restrict__ bl1,
    float* __restrict__ out0, float* __restrict__ out1,
    int N0, int N1, int nblk0)
{
    __shared__ unsigned short s[32 * APAD];
    const int rel = (blockIdx.x >= nblk0);
    const int nb = (rel ? blockIdx.x - nblk0 : blockIdx.x) * 32;
    const float* xd = rel ? xd1 : xd0;
    const unsigned short* ag = rel ? ag1 : ag0;
    const float* bl = rel ? bl1 : bl0;
    float* outp = rel ? out1 : out0;
    const int N = rel ? N1 : N0;
    const unsigned short* wf = wfrag + (size_t)rel * 4096 * 8;

    {
        int t = threadIdx.x;
        int r = t >> 3;
        int c0 = (t & 7) * 16;
        int n = nb + r;
        unsigned short* drow = s + r * APAD;
        if (n < N) {
            const float4* srcp = (const float4*)(xd + (size_t)n * CCH + c0);
#pragma unroll
            for (int qq = 0; qq < 4; qq++) {
                float4 v = srcp[qq];
                unsigned u0 = (unsigned)f2bf(v.x) | ((unsigned)f2bf(v.y) << 16);
                unsigned u1 = (unsigned)f2bf(v.z) | ((unsigned)f2bf(v.w) << 16);
                *(uint2*)(drow + c0 + qq * 4) = make_uint2(u0, u1);
            }
            const uint4* ap = (const uint4*)(ag + (size_t)n * CCH + c0);
            *(uint4*)(drow + CCH + c0) = ap[0];
            *(uint4*)(drow + CCH + c0 + 8) = ap[1];
        } else {
            uint4 z = make_uint4(0u, 0u, 0u, 0u);
            *(uint4*)(drow + c0) = z;
            *(uint4*)(drow + c0 + 8) = z;
            *(uint4*)(drow + CCH + c0) = z;
            *(uint4*)(drow + CCH + c0 + 8) = z;
        }
    }
    __syncthreads();

    const int tid = threadIdx.x;
    const int w = tid >> 6;
    const int l = tid & 63;
    const int mt = w & 1;
    const int ctb = (w >> 1) * 4;
    const int q = l >> 4;
    const int m16 = l & 15;

    floatx4 acc[4];
#pragma unroll
    for (int c = 0; c < 4; c++) acc[c] = (floatx4){0.f, 0.f, 0.f, 0.f};

    const unsigned short* arow = s + (mt * 16 + m16) * APAD + q * 8;
#pragma unroll
    for (int kc = 0; kc < 8; kc++) {
        short8 af = *(const short8*)(arow + kc * 32);
#pragma unroll
        for (int c = 0; c < 4; c++) {
            const unsigned short* bp = wf + ((((size_t)(ctb + c)) * 8 + kc) * 64 + l) * 8;
            short8 bv = *(const short8*)bp;
            acc[c] = __builtin_amdgcn_mfma_f32_16x16x32_bf16(af, bv, acc[c], 0, 0, 0);
        }
    }

#pragma unroll
    for (int c = 0; c < 4; c++) {
        const int col = (ctb + c) * 16 + m16;
        const float bv = bl[col];
#pragma unroll
        for (int r = 0; r < 4; r++) {
            const int node = nb + mt * 16 + q * 4 + r;
            if (node < N) outp[(size_t)node * CCH + col] = fmaxf(acc[c][r] + bv, 0.0f);
        }
    }
}

extern "C" void kernel_launch(void* const* d_in, const int* in_sizes, int n_in,
                              void* d_out, int out_size, void* d_ws, size_t ws_size,
                              hipStream_t stream) {
    const float* x_a      = (const float*)d_in[0];
    const float* x_b      = (const float*)d_in[1];
    const int*   e_ab     = (const int*)d_in[2];
    const int*   e_ba     = (const int*)d_in[3];
    const float* W_ih_ab  = (const float*)d_in[4];
    const float* b_ab     = (const float*)d_in[5];
    const float* W_lin_ab = (const float*)d_in[6];
    const float* b_lin_ab = (const float*)d_in[7];
    const float* W_ih_ba  = (const float*)d_in[8];
    const float* b_ba     = (const float*)d_in[9];
    const float* W_lin_ba = (const float*)d_in[10];
    const float* b_lin_ba = (const float*)d_in[11];

    const int NA = in_sizes[0] / CCH;
    const int NB = in_sizes[1] / CCH;
    const int E0 = in_sizes[2] / 2;   // a->b (dst in B)
    const int E1 = in_sizes[3] / 2;   // b->a (dst in A)

    float* out = (float*)d_out;
    char* ws = (char*)d_ws;
    size_t off = 0;
    auto alloc = [&](size_t bytes) { char* p = ws + off; off += (bytes + 255) & ~(size_t)255; return p; };

    unsigned short* wfrag_ih  = (unsigned short*)alloc(12288 * 8 * 2);
    unsigned short* wfrag_lin = (unsigned short*)alloc(8192 * 8 * 2);
    unsigned short* msg_a     = (unsigned short*)alloc((size_t)NA * CCH * 2);
    unsigned short* msg_b     = (unsigned short*)alloc((size_t)NB * CCH * 2);
    unsigned short* aggr_b    = (unsigned short*)alloc((size_t)NB * CCH * 2);
    unsigned short* aggr_a    = (unsigned short*)alloc((size_t)NA * CCH * 2);

    const int nbkt0 = (NB + 255) / 256;   // rel0 coarse buckets (dst in B)
    const int nbkt1 = (NA + 255) / 256;   // rel1 (dst in A)
    const int NBKT = nbkt0 + nbkt1;
    const long long Etot = (long long)E0 + E1;
    const int nT = (int)((Etot + TK - 1) / TK);

    int* H      = (int*)alloc((size_t)nT * NBKT * 4);
    int* btot   = (int*)alloc((size_t)NBKT * 4);
    int* coff   = (int*)alloc((size_t)NBKT * 4);
    int* offs_b = (int*)alloc((size_t)NB * 4);
    int* offs_a = (int*)alloc((size_t)NA * 4);
    int* deg_b  = (int*)alloc((size_t)NB * 4);
    int* deg_a  = (int*)alloc((size_t)NA * 4);
    unsigned* packed = (unsigned*)alloc((size_t)Etot * 4);  // becomes csr after fine sort

    const int nblkA = (NA + 31) / 32;
    const int nblkB = (NB + 31) / 32;

    prep_wih_kernel<<<48, 256, 0, stream>>>(W_ih_ab, W_ih_ba, wfrag_ih);
    prep_wlin_kernel<<<32, 256, 0, stream>>>(W_lin_ab, W_lin_ba, wfrag_lin);

    // rel0: a->b (src A, msg_a); rel1: b->a (src B, msg_b)
    lstm_mfma_kernel<<<nblkA + nblkB, 256, 0, stream>>>(
        x_a, x_b, wfrag_ih, b_ab, b_ba, msg_a, msg_b, NA, NB, nblkA);

    tile_hist_kernel<<<nT, 256, 0, stream>>>(e_ab + E0, e_ba + E1, H, E0, E1, nbkt0, NBKT);
    colscan_kernel<<<NBKT, 256, 0, stream>>>(H, btot, nT, NBKT);
    scanb_kernel<<<1, 256, 0, stream>>>(btot, coff, NBKT);
    tile_scatter_kernel<<<nT, 256, 0, stream>>>(
        e_ab, e_ab + E0, e_ba, e_ba + E1, H, coff, packed, E0, E1, nbkt0, NBKT);
    fine_sort_kernel<<<NBKT, 256, 0, stream>>>(
        packed, coff, btot, offs_b, deg_b, offs_a, deg_a, NB, NA, nbkt0);

    gather_kernel<<<(NB + NA + 3) / 4, 256, 0, stream>>>(
        msg_a, msg_b, (const int*)packed, offs_b, offs_a, deg_b, deg_a, aggr_b, aggr_a, NB, NA);

    // rel0 output -> out_b (index 1), rel1 -> out_a (index 0)
    linear_mfma_kernel<<<nblkB + nblkA, 256, 0, stream>>>(
        x_b, x_a, aggr_b, aggr_a, wfrag_lin, b_lin_ab, b_lin_ba,
        out + (size_t)NA * CCH, out, NB, NA, nblkB);
}

// Round 6
// 286.590 us; speedup vs baseline: 3.0260x; 1.1282x over previous
//
#include <hip/hip_runtime.h>
#include <cstdint>
#include <cstddef>

#define CCH 128
#define TK 8192      // edges per tile in CSR build
#define FCAP 8192    // fine-sort bucket capacity (mean ~4096)
#define MAXBKT 512   // max coarse buckets (392 actual)
#define XPAD 136     // 128 + 8 bf16 pad
#define APAD 264     // 256 + 8 pad

typedef __attribute__((ext_vector_type(8))) short short8;
typedef __attribute__((ext_vector_type(4))) float floatx4;

__device__ __forceinline__ unsigned short f2bf(float f) {
    unsigned u = __builtin_bit_cast(unsigned, f);
    u += 0x7fffu + ((u >> 16) & 1u);   // RNE
    return (unsigned short)(u >> 16);
}
__device__ __forceinline__ float bf2f(unsigned short h) {
    unsigned u = ((unsigned)h) << 16;
    return __builtin_bit_cast(float, u);
}
__device__ __forceinline__ float sigmoidf_(float x) { return 1.0f / (1.0f + __expf(-x)); }

// ---------------- merged weight prep: fragment-ready bf16 ----------------
// W_ih frags: [rel][g(3)][ct(8)][kc(4)][lane(64)][j(8)], gates {i,g,o}->rows{0,256,384}
// W_lin frags: [rel][ct(8)][kc(8)][lane(64)][j(8)]
__global__ __launch_bounds__(256) void prep_weights_kernel(
    const float* __restrict__ Wih0, const float* __restrict__ Wih1,
    const float* __restrict__ Wlin0, const float* __restrict__ Wlin1,
    unsigned short* __restrict__ frag_ih, unsigned short* __restrict__ frag_lin)
{
    int t = blockIdx.x * 256 + threadIdx.x;
    if (t < 12288) {
        int l  = t & 63;
        int kc = (t >> 6) & 3;
        int ct = (t >> 8) & 7;
        int g  = (t >> 11) % 3;
        int rel = t / 6144;
        int gb = (g == 0) ? 0 : (g == 1 ? 256 : 384);
        const float* W = rel ? Wih1 : Wih0;
        int n  = gb + ct * 16 + (l & 15);
        int kb = kc * 32 + (l >> 4) * 8;
        unsigned short* o = frag_ih + (size_t)t * 8;
#pragma unroll
        for (int j = 0; j < 8; j++) o[j] = f2bf(W[(size_t)n * CCH + kb + j]);
    } else {
        int t2 = t - 12288;
        if (t2 >= 8192) return;
        int l  = t2 & 63;
        int kc = (t2 >> 6) & 7;
        int ct = (t2 >> 9) & 7;
        int rel = t2 >> 12;
        const float* W = rel ? Wlin1 : Wlin0;
        int n  = ct * 16 + (l & 15);
        int kb = kc * 32 + (l >> 4) * 8;
        unsigned short* o = frag_lin + (size_t)t2 * 8;
#pragma unroll
        for (int j = 0; j < 8; j++) o[j] = f2bf(W[(size_t)n * 256 + kb + j]);
    }
}

// ---------------- LSTM message via MFMA + fused edge histogram ----------------
// blocks [0,nT): per-tile LDS histogram over coarse buckets (dst>>8) -> H rows.
// blocks [nT, nT+nblk0+nblk1): LSTM GEMM, 32 nodes/block.
// Wave layout (GEMM): wave w covers ct {2w,2w+1} x m-tiles {0,1} -> B-frag reuse x2.
__global__ __launch_bounds__(256) void lstm_hist_kernel(
    const float* __restrict__ x0, const float* __restrict__ x1,
    const unsigned short* __restrict__ wfrag,
    const float* __restrict__ b0, const float* __restrict__ b1,
    unsigned short* __restrict__ msg0, unsigned short* __restrict__ msg1,
    int N0, int N1, int nblk0,
    const int* __restrict__ dstE0, const int* __restrict__ dstE1,
    int* __restrict__ H, int E0, int E1, int nbkt0, int NBKT, int nT)
{
    __shared__ unsigned short xs[32 * XPAD];
    __shared__ int h[MAXBKT];
    const int tid = threadIdx.x;

    if (blockIdx.x < nT) {   // ---- histogram tile ----
        for (int i = tid; i < NBKT; i += 256) h[i] = 0;
        __syncthreads();
        const long long Etot = (long long)E0 + E1;
        const long long base = (long long)blockIdx.x * TK;
        for (int i = tid; i < TK; i += 256) {
            long long e = base + i;
            if (e >= Etot) break;
            int g;
            if (e < E0) g = dstE0[e] >> 8;
            else        g = nbkt0 + (dstE1[e - E0] >> 8);
            atomicAdd(&h[g], 1);
        }
        __syncthreads();
        int* row = H + (size_t)blockIdx.x * NBKT;
        for (int i = tid; i < NBKT; i += 256) row[i] = h[i];
        return;
    }

    // ---- LSTM GEMM ----
    const int lb = blockIdx.x - nT;
    const int rel = (lb >= nblk0);
    const int nb = (rel ? (lb - nblk0) : lb) * 32;
    const float* x = rel ? x1 : x0;
    const float* bias = rel ? b1 : b0;
    unsigned short* msg = rel ? msg1 : msg0;
    const int N = rel ? N1 : N0;
    const unsigned short* wf = wfrag + (size_t)rel * 6144 * 8;

    {
        int r = tid >> 3;
        int c0 = (tid & 7) * 16;
        int n = nb + r;
        unsigned short* dstp = xs + r * XPAD + c0;
        if (n < N) {
            const float4* srcp = (const float4*)(x + (size_t)n * CCH + c0);
#pragma unroll
            for (int qq = 0; qq < 4; qq++) {
                float4 v = srcp[qq];
                unsigned u0 = (unsigned)f2bf(v.x) | ((unsigned)f2bf(v.y) << 16);
                unsigned u1 = (unsigned)f2bf(v.z) | ((unsigned)f2bf(v.w) << 16);
                *(uint2*)(dstp + qq * 4) = make_uint2(u0, u1);
            }
        } else {
#pragma unroll
            for (int qq = 0; qq < 4; qq++) *(uint2*)(dstp + qq * 4) = make_uint2(0u, 0u);
        }
    }
    __syncthreads();

    const int w = tid >> 6;
    const int l = tid & 63;
    const int ctb2 = w * 2;             // 2 col-tiles per wave
    const int q = l >> 4;
    const int m16 = l & 15;

    floatx4 acc[3][2][2];               // [gate][ct][mt]
#pragma unroll
    for (int g = 0; g < 3; g++)
#pragma unroll
        for (int c = 0; c < 2; c++)
#pragma unroll
            for (int mt = 0; mt < 2; mt++) acc[g][c][mt] = (floatx4){0.f, 0.f, 0.f, 0.f};

    const unsigned short* arow0 = xs + m16 * XPAD + q * 8;
    const unsigned short* arow1 = xs + (16 + m16) * XPAD + q * 8;
#pragma unroll
    for (int kc = 0; kc < 4; kc++) {
        short8 af0 = *(const short8*)(arow0 + kc * 32);
        short8 af1 = *(const short8*)(arow1 + kc * 32);
#pragma unroll
        for (int g = 0; g < 3; g++)
#pragma unroll
            for (int c = 0; c < 2; c++) {
                const unsigned short* bp = wf + ((((size_t)g * 8 + (ctb2 + c)) * 4 + kc) * 64 + l) * 8;
                short8 bv = *(const short8*)bp;
                acc[g][c][0] = __builtin_amdgcn_mfma_f32_16x16x32_bf16(af0, bv, acc[g][c][0], 0, 0, 0);
                acc[g][c][1] = __builtin_amdgcn_mfma_f32_16x16x32_bf16(af1, bv, acc[g][c][1], 0, 0, 0);
            }
    }

#pragma unroll
    for (int c = 0; c < 2; c++) {
        const int col = (ctb2 + c) * 16 + m16;
        const float bi = bias[col], bg = bias[256 + col], bo = bias[384 + col];
#pragma unroll
        for (int mt = 0; mt < 2; mt++)
#pragma unroll
            for (int r = 0; r < 4; r++) {
                const int node = nb + mt * 16 + q * 4 + r;
                if (node < N) {
                    float iv = sigmoidf_(acc[0][c][mt][r] + bi);
                    float gv = tanhf(acc[1][c][mt][r] + bg);
                    float ov = sigmoidf_(acc[2][c][mt][r] + bo);
                    msg[(size_t)node * CCH + col] = f2bf(ov * tanhf(iv * gv));
                }
            }
    }
}

// Pass 2a: per-bucket exclusive scan over tiles (in place), bucket totals out.
__global__ __launch_bounds__(256) void colscan_kernel(
    int* __restrict__ H, int* __restrict__ btot, int nT, int NBKT)
{
    __shared__ int s[256];
    __shared__ int carry;
    const int g = blockIdx.x;
    const int tid = threadIdx.x;
    if (tid == 0) carry = 0;
    __syncthreads();
    for (int base = 0; base < nT; base += 256) {
        int b = base + tid;
        int v = (b < nT) ? H[(size_t)b * NBKT + g] : 0;
        s[tid] = v;
        __syncthreads();
#pragma unroll
        for (int off = 1; off < 256; off <<= 1) {
            int t = (tid >= off) ? s[tid - off] : 0;
            __syncthreads();
            s[tid] += t;
            __syncthreads();
        }
        if (b < nT) H[(size_t)b * NBKT + g] = s[tid] - v + carry;
        __syncthreads();
        if (tid == 255) carry += s[255];
        __syncthreads();
    }
    if (tid == 0) btot[g] = carry;
}

// Pass 2b: single-block exclusive scan of bucket totals -> coff.
__global__ __launch_bounds__(256) void scanb_kernel(
    const int* __restrict__ btot, int* __restrict__ coff, int NBKT)
{
    __shared__ int s[256];
    __shared__ int carry;
    const int tid = threadIdx.x;
    if (tid == 0) carry = 0;
    __syncthreads();
    for (int base = 0; base < NBKT; base += 256) {
        int i = base + tid;
        int v = (i < NBKT) ? btot[i] : 0;
        s[tid] = v;
        __syncthreads();
#pragma unroll
        for (int off = 1; off < 256; off <<= 1) {
            int t = (tid >= off) ? s[tid - off] : 0;
            __syncthreads();
            s[tid] += t;
            __syncthreads();
        }
        if (i < NBKT) coff[i] = s[tid] - v + carry;
        __syncthreads();
        if (tid == 255) carry += s[255];
        __syncthreads();
    }
}

// Pass 3: re-read edges; LDS cursors = coff[g]+H[tile][g]; write packed (dst&255)<<24|src.
__global__ __launch_bounds__(256) void tile_scatter_kernel(
    const int* __restrict__ src0, const int* __restrict__ dst0,
    const int* __restrict__ src1, const int* __restrict__ dst1,
    const int* __restrict__ H, const int* __restrict__ coff,
    unsigned* __restrict__ packed, int E0, int E1, int nbkt0, int NBKT)
{
    __shared__ int cur[MAXBKT];
    const int tid = threadIdx.x;
    const int* row = H + (size_t)blockIdx.x * NBKT;
    for (int i = tid; i < NBKT; i += 256) cur[i] = coff[i] + row[i];
    __syncthreads();
    const long long Etot = (long long)E0 + E1;
    const long long base = (long long)blockIdx.x * TK;
    for (int i = tid; i < TK; i += 256) {
        long long e = base + i;
        if (e >= Etot) break;
        int s, g, k;
        if (e < E0) { int d = dst0[e]; s = src0[e]; g = d >> 8; k = d & 255; }
        else { long long ee = e - E0; int d = dst1[ee]; s = src1[ee]; g = nbkt0 + (d >> 8); k = d & 255; }
        int pos = atomicAdd(&cur[g], 1);
        packed[pos] = ((unsigned)k << 24) | (unsigned)s;
    }
}

// Pass 4: one block per bucket; in-LDS counting sort by 8-bit key; emit deg/offs.
__global__ __launch_bounds__(256) void fine_sort_kernel(
    unsigned* __restrict__ packed, const int* __restrict__ coff, const int* __restrict__ btot,
    int* __restrict__ offs0, int* __restrict__ deg0,
    int* __restrict__ offs1, int* __restrict__ deg1,
    int N0, int N1, int nbkt0)
{
    __shared__ unsigned pin[FCAP];
    __shared__ int sout[FCAP];
    __shared__ int hist[256], scn[256], cur[256];
    const int g = blockIdx.x;
    const int tid = threadIdx.x;
    const int base = coff[g];
    const int cnt = min(btot[g], FCAP);

    for (int i = tid; i < cnt; i += 256) pin[i] = packed[base + i];
    hist[tid] = 0;
    __syncthreads();
    for (int i = tid; i < cnt; i += 256) atomicAdd(&hist[pin[i] >> 24], 1);
    __syncthreads();
    int v = hist[tid];
    scn[tid] = v;
    __syncthreads();
#pragma unroll
    for (int off = 1; off < 256; off <<= 1) {
        int t = (tid >= off) ? scn[tid - off] : 0;
        __syncthreads();
        scn[tid] += t;
        __syncthreads();
    }
    int excl = scn[tid] - v;
    cur[tid] = excl;
    {
        const int rel = (g >= nbkt0);
        const int lb = rel ? g - nbkt0 : g;
        const int n = lb * 256 + tid;
        const int N = rel ? N1 : N0;
        if (n < N) {
            if (rel) { offs1[n] = base + excl; deg1[n] = v; }
            else     { offs0[n] = base + excl; deg0[n] = v; }
        }
    }
    __syncthreads();
    for (int i = tid; i < cnt; i += 256) {
        unsigned p = pin[i];
        int pos = atomicAdd(&cur[p >> 24], 1);
        sout[pos] = (int)(p & 0x00FFFFFFu);
    }
    __syncthreads();
    int* op = (int*)packed;
    for (int i = tid; i < cnt; i += 256) op[base + i] = sout[i];
}

// ---------------- gather: one wave per dst node, 8-deep MLP ----------------
__global__ __launch_bounds__(256) void gather_kernel(
    const unsigned short* __restrict__ msg0, const unsigned short* __restrict__ msg1,
    const int* __restrict__ csr,
    const int* __restrict__ offs0, const int* __restrict__ offs1,
    const int* __restrict__ deg0, const int* __restrict__ deg1,
    unsigned short* __restrict__ aggr0, unsigned short* __restrict__ aggr1,
    int N0, int N1)
{
    const int wv = blockIdx.x * 4 + (threadIdx.x >> 6);
    const int l = threadIdx.x & 63;
    const unsigned short* msg; unsigned short* aggr;
    int n, start, cnt;
    if (wv < N0)            { n = wv;      msg = msg0; start = offs0[n]; cnt = deg0[n]; aggr = aggr0; }
    else if (wv < N0 + N1)  { n = wv - N0; msg = msg1; start = offs1[n]; cnt = deg1[n]; aggr = aggr1; }
    else return;

    float ax = 0.f, ay = 0.f;
    const int* ce = csr + start;
    const unsigned short* mb = msg + l * 2;
    int j = 0;
    for (; j + 8 <= cnt; j += 8) {
        int s0 = ce[j], s1 = ce[j + 1], s2 = ce[j + 2], s3 = ce[j + 3];
        int s4 = ce[j + 4], s5 = ce[j + 5], s6 = ce[j + 6], s7 = ce[j + 7];
        unsigned u0 = *(const unsigned*)(mb + (size_t)s0 * CCH);
        unsigned u1 = *(const unsigned*)(mb + (size_t)s1 * CCH);
        unsigned u2 = *(const unsigned*)(mb + (size_t)s2 * CCH);
        unsigned u3 = *(const unsigned*)(mb + (size_t)s3 * CCH);
        unsigned u4 = *(const unsigned*)(mb + (size_t)s4 * CCH);
        unsigned u5 = *(const unsigned*)(mb + (size_t)s5 * CCH);
        unsigned u6 = *(const unsigned*)(mb + (size_t)s6 * CCH);
        unsigned u7 = *(const unsigned*)(mb + (size_t)s7 * CCH);
        ax += bf2f((unsigned short)u0) + bf2f((unsigned short)u1)
            + bf2f((unsigned short)u2) + bf2f((unsigned short)u3)
            + bf2f((unsigned short)u4) + bf2f((unsigned short)u5)
            + bf2f((unsigned short)u6) + bf2f((unsigned short)u7);
        ay += bf2f((unsigned short)(u0 >> 16)) + bf2f((unsigned short)(u1 >> 16))
            + bf2f((unsigned short)(u2 >> 16)) + bf2f((unsigned short)(u3 >> 16))
            + bf2f((unsigned short)(u4 >> 16)) + bf2f((unsigned short)(u5 >> 16))
            + bf2f((unsigned short)(u6 >> 16)) + bf2f((unsigned short)(u7 >> 16));
    }
    for (; j + 4 <= cnt; j += 4) {
        int s0 = ce[j], s1 = ce[j + 1], s2 = ce[j + 2], s3 = ce[j + 3];
        unsigned u0 = *(const unsigned*)(mb + (size_t)s0 * CCH);
        unsigned u1 = *(const unsigned*)(mb + (size_t)s1 * CCH);
        unsigned u2 = *(const unsigned*)(mb + (size_t)s2 * CCH);
        unsigned u3 = *(const unsigned*)(mb + (size_t)s3 * CCH);
        ax += bf2f((unsigned short)u0) + bf2f((unsigned short)u1)
            + bf2f((unsigned short)u2) + bf2f((unsigned short)u3);
        ay += bf2f((unsigned short)(u0 >> 16)) + bf2f((unsigned short)(u1 >> 16))
            + bf2f((unsigned short)(u2 >> 16)) + bf2f((unsigned short)(u3 >> 16));
    }
    for (; j < cnt; j++) {
        unsigned u0 = *(const unsigned*)(mb + (size_t)ce[j] * CCH);
        ax += bf2f((unsigned short)u0);
        ay += bf2f((unsigned short)(u0 >> 16));
    }
    unsigned o = (unsigned)f2bf(ax) | ((unsigned)f2bf(ay) << 16);
    *(unsigned*)(aggr + (size_t)n * CCH + l * 2) = o;
}

// ---------------- final linear via MFMA (wave = 2 ct x 2 mt) ----------------
__global__ __launch_bounds__(256) void linear_mfma_kernel(
    const float* __restrict__ xd0, const float* __restrict__ xd1,
    const unsigned short* __restrict__ ag0, const unsigned short* __restrict__ ag1,
    const unsigned short* __restrict__ wfrag,
    const float* __restrict__ bl0, const float* __restrict__ bl1,
    float* __restrict__ out0, float* __restrict__ out1,
    int N0, int N1, int nblk0)
{
    __shared__ unsigned short s[32 * APAD];
    const int rel = (blockIdx.x >= nblk0);
    const int nb = (rel ? blockIdx.x - nblk0 : blockIdx.x) * 32;
    const float* xd = rel ? xd1 : xd0;
    const unsigned short* ag = rel ? ag1 : ag0;
    const float* bl = rel ? bl1 : bl0;
    float* outp = rel ? out1 : out0;
    const int N = rel ? N1 : N0;
    const unsigned short* wf = wfrag + (size_t)rel * 4096 * 8;

    {
        int t = threadIdx.x;
        int r = t >> 3;
        int c0 = (t & 7) * 16;
        int n = nb + r;
        unsigned short* drow = s + r * APAD;
        if (n < N) {
            const float4* srcp = (const float4*)(xd + (size_t)n * CCH + c0);
#pragma unroll
            for (int qq = 0; qq < 4; qq++) {
                float4 v = srcp[qq];
                unsigned u0 = (unsigned)f2bf(v.x) | ((unsigned)f2bf(v.y) << 16);
                unsigned u1 = (unsigned)f2bf(v.z) | ((unsigned)f2bf(v.w) << 16);
                *(uint2*)(drow + c0 + qq * 4) = make_uint2(u0, u1);
            }
            const uint4* ap = (const uint4*)(ag + (size_t)n * CCH + c0);
            *(uint4*)(drow + CCH + c0) = ap[0];
            *(uint4*)(drow + CCH + c0 + 8) = ap[1];
        } else {
            uint4 z = make_uint4(0u, 0u, 0u, 0u);
            *(uint4*)(drow + c0) = z;
            *(uint4*)(drow + c0 + 8) = z;
            *(uint4*)(drow + CCH + c0) = z;
            *(uint4*)(drow + CCH + c0 + 8) = z;
        }
    }
    __syncthreads();

    const int tid = threadIdx.x;
    const int w = tid >> 6;
    const int l = tid & 63;
    const int ctb2 = w * 2;
    const int q = l >> 4;
    const int m16 = l & 15;

    floatx4 acc[2][2];                   // [ct][mt]
#pragma unroll
    for (int c = 0; c < 2; c++)
#pragma unroll
        for (int mt = 0; mt < 2; mt++) acc[c][mt] = (floatx4){0.f, 0.f, 0.f, 0.f};

    const unsigned short* arow0 = s + m16 * APAD + q * 8;
    const unsigned short* arow1 = s + (16 + m16) * APAD + q * 8;
#pragma unroll
    for (int kc = 0; kc < 8; kc++) {
        short8 af0 = *(const short8*)(arow0 + kc * 32);
        short8 af1 = *(const short8*)(arow1 + kc * 32);
#pragma unroll
        for (int c = 0; c < 2; c++) {
            const unsigned short* bp = wf + ((((size_t)(ctb2 + c)) * 8 + kc) * 64 + l) * 8;
            short8 bv = *(const short8*)bp;
            acc[c][0] = __builtin_amdgcn_mfma_f32_16x16x32_bf16(af0, bv, acc[c][0], 0, 0, 0);
            acc[c][1] = __builtin_amdgcn_mfma_f32_16x16x32_bf16(af1, bv, acc[c][1], 0, 0, 0);
        }
    }

#pragma unroll
    for (int c = 0; c < 2; c++) {
        const int col = (ctb2 + c) * 16 + m16;
        const float bv = bl[col];
#pragma unroll
        for (int mt = 0; mt < 2; mt++)
#pragma unroll
            for (int r = 0; r < 4; r++) {
                const int node = nb + mt * 16 + q * 4 + r;
                if (node < N) outp[(size_t)node * CCH + col] = fmaxf(acc[c][mt][r] + bv, 0.0f);
            }
    }
}

extern "C" void kernel_launch(void* const* d_in, const int* in_sizes, int n_in,
                              void* d_out, int out_size, void* d_ws, size_t ws_size,
                              hipStream_t stream) {
    const float* x_a      = (const float*)d_in[0];
    const float* x_b      = (const float*)d_in[1];
    const int*   e_ab     = (const int*)d_in[2];
    const int*   e_ba     = (const int*)d_in[3];
    const float* W_ih_ab  = (const float*)d_in[4];
    const float* b_ab     = (const float*)d_in[5];
    const float* W_lin_ab = (const float*)d_in[6];
    const float* b_lin_ab = (const float*)d_in[7];
    const float* W_ih_ba  = (const float*)d_in[8];
    const float* b_ba     = (const float*)d_in[9];
    const float* W_lin_ba = (const float*)d_in[10];
    const float* b_lin_ba = (const float*)d_in[11];

    const int NA = in_sizes[0] / CCH;
    const int NB = in_sizes[1] / CCH;
    const int E0 = in_sizes[2] / 2;   // a->b (dst in B)
    const int E1 = in_sizes[3] / 2;   // b->a (dst in A)

    float* out = (float*)d_out;
    char* ws = (char*)d_ws;
    size_t off = 0;
    auto alloc = [&](size_t bytes) { char* p = ws + off; off += (bytes + 255) & ~(size_t)255; return p; };

    unsigned short* wfrag_ih  = (unsigned short*)alloc(12288 * 8 * 2);
    unsigned short* wfrag_lin = (unsigned short*)alloc(8192 * 8 * 2);
    unsigned short* msg_a     = (unsigned short*)alloc((size_t)NA * CCH * 2);
    unsigned short* msg_b     = (unsigned short*)alloc((size_t)NB * CCH * 2);
    unsigned short* aggr_b    = (unsigned short*)alloc((size_t)NB * CCH * 2);
    unsigned short* aggr_a    = (unsigned short*)alloc((size_t)NA * CCH * 2);

    const int nbkt0 = (NB + 255) / 256;   // rel0 coarse buckets (dst in B)
    const int nbkt1 = (NA + 255) / 256;   // rel1 (dst in A)
    const int NBKT = nbkt0 + nbkt1;
    const long long Etot = (long long)E0 + E1;
    const int nT = (int)((Etot + TK - 1) / TK);

    int* H      = (int*)alloc((size_t)nT * NBKT * 4);
    int* btot   = (int*)alloc((size_t)NBKT * 4);
    int* coff   = (int*)alloc((size_t)NBKT * 4);
    int* offs_b = (int*)alloc((size_t)NB * 4);
    int* offs_a = (int*)alloc((size_t)NA * 4);
    int* deg_b  = (int*)alloc((size_t)NB * 4);
    int* deg_a  = (int*)alloc((size_t)NA * 4);
    unsigned* packed = (unsigned*)alloc((size_t)Etot * 4);  // becomes csr after fine sort

    const int nblkA = (NA + 31) / 32;
    const int nblkB = (NB + 31) / 32;

    prep_weights_kernel<<<80, 256, 0, stream>>>(
        W_ih_ab, W_ih_ba, W_lin_ab, W_lin_ba, wfrag_ih, wfrag_lin);

    // fused: blocks [0,nT) = edge histogram; rest = LSTM GEMM (rel0: a->b src A; rel1: b->a src B)
    lstm_hist_kernel<<<nT + nblkA + nblkB, 256, 0, stream>>>(
        x_a, x_b, wfrag_ih, b_ab, b_ba, msg_a, msg_b, NA, NB, nblkA,
        e_ab + E0, e_ba + E1, H, E0, E1, nbkt0, NBKT, nT);

    colscan_kernel<<<NBKT, 256, 0, stream>>>(H, btot, nT, NBKT);
    scanb_kernel<<<1, 256, 0, stream>>>(btot, coff, NBKT);
    tile_scatter_kernel<<<nT, 256, 0, stream>>>(
        e_ab, e_ab + E0, e_ba, e_ba + E1, H, coff, packed, E0, E1, nbkt0, NBKT);
    fine_sort_kernel<<<NBKT, 256, 0, stream>>>(
        packed, coff, btot, offs_b, deg_b, offs_a, deg_a, NB, NA, nbkt0);

    gather_kernel<<<(NB + NA + 3) / 4, 256, 0, stream>>>(
        msg_a, msg_b, (const int*)packed, offs_b, offs_a, deg_b, deg_a, aggr_b, aggr_a, NB, NA);

    // rel0 output -> out_b (index 1), rel1 -> out_a (index 0)
    linear_mfma_kernel<<<nblkB + nblkA, 256, 0, stream>>>(
        x_b, x_a, aggr_b, aggr_a, wfrag_lin, b_lin_ab, b_lin_ba,
        out + (size_t)NA * CCH, out, NB, NA, nblkB);
}

// Round 7
// 279.770 us; speedup vs baseline: 3.0998x; 1.0244x over previous
//
#include <hip/hip_runtime.h>
#include <cstdint>
#include <cstddef>

#define CCH 128
#define TK 8192      // edges per tile in CSR build
#define FCAP 8192    // fine-sort bucket capacity == fixed slot size
#define SLOT 8192    // fixed packed-array slot per coarse bucket
#define MAXBKT 512   // max coarse buckets (392 actual)
#define XPAD 136     // 128 + 8 bf16 pad
#define APAD 264     // 256 + 8 pad

typedef __attribute__((ext_vector_type(8))) short short8;
typedef __attribute__((ext_vector_type(4))) float floatx4;

__device__ __forceinline__ unsigned short f2bf(float f) {
    unsigned u = __builtin_bit_cast(unsigned, f);
    u += 0x7fffu + ((u >> 16) & 1u);   // RNE
    return (unsigned short)(u >> 16);
}
__device__ __forceinline__ float bf2f(unsigned short h) {
    unsigned u = ((unsigned)h) << 16;
    return __builtin_bit_cast(float, u);
}
__device__ __forceinline__ float sigmoidf_(float x) { return 1.0f / (1.0f + __expf(-x)); }
__device__ __forceinline__ float tanh_fast(float x) {
    x = fminf(fmaxf(x, -10.0f), 10.0f);
    float e = __expf(2.0f * x);
    return (e - 1.0f) / (e + 1.0f);
}

// ---------------- merged weight prep: fragment-ready bf16 ----------------
__global__ __launch_bounds__(256) void prep_weights_kernel(
    const float* __restrict__ Wih0, const float* __restrict__ Wih1,
    const float* __restrict__ Wlin0, const float* __restrict__ Wlin1,
    unsigned short* __restrict__ frag_ih, unsigned short* __restrict__ frag_lin)
{
    int t = blockIdx.x * 256 + threadIdx.x;
    if (t < 12288) {
        int l  = t & 63;
        int kc = (t >> 6) & 3;
        int ct = (t >> 8) & 7;
        int g  = (t >> 11) % 3;
        int rel = t / 6144;
        int gb = (g == 0) ? 0 : (g == 1 ? 256 : 384);
        const float* W = rel ? Wih1 : Wih0;
        int n  = gb + ct * 16 + (l & 15);
        int kb = kc * 32 + (l >> 4) * 8;
        unsigned short* o = frag_ih + (size_t)t * 8;
#pragma unroll
        for (int j = 0; j < 8; j++) o[j] = f2bf(W[(size_t)n * CCH + kb + j]);
    } else {
        int t2 = t - 12288;
        if (t2 >= 8192) return;
        int l  = t2 & 63;
        int kc = (t2 >> 6) & 7;
        int ct = (t2 >> 9) & 7;
        int rel = t2 >> 12;
        const float* W = rel ? Wlin1 : Wlin0;
        int n  = ct * 16 + (l & 15);
        int kb = kc * 32 + (l >> 4) * 8;
        unsigned short* o = frag_lin + (size_t)t2 * 8;
#pragma unroll
        for (int j = 0; j < 8; j++) o[j] = f2bf(W[(size_t)n * 256 + kb + j]);
    }
}

// ---------------- LSTM message via MFMA + fused edge histogram ----------------
__global__ __launch_bounds__(256) void lstm_hist_kernel(
    const float* __restrict__ x0, const float* __restrict__ x1,
    const unsigned short* __restrict__ wfrag,
    const float* __restrict__ b0, const float* __restrict__ b1,
    unsigned short* __restrict__ msg0, unsigned short* __restrict__ msg1,
    int N0, int N1, int nblk0,
    const int* __restrict__ dstE0, const int* __restrict__ dstE1,
    int* __restrict__ H, int E0, int E1, int nbkt0, int NBKT, int nT)
{
    __shared__ unsigned short xs[32 * XPAD];
    __shared__ int h[MAXBKT];
    const int tid = threadIdx.x;

    if (blockIdx.x < nT) {   // ---- histogram tile ----
        for (int i = tid; i < NBKT; i += 256) h[i] = 0;
        __syncthreads();
        const long long Etot = (long long)E0 + E1;
        const long long base = (long long)blockIdx.x * TK;
        for (int i = tid; i < TK; i += 256) {
            long long e = base + i;
            if (e >= Etot) break;
            int g;
            if (e < E0) g = dstE0[e] >> 8;
            else        g = nbkt0 + (dstE1[e - E0] >> 8);
            atomicAdd(&h[g], 1);
        }
        __syncthreads();
        int* row = H + (size_t)blockIdx.x * NBKT;
        for (int i = tid; i < NBKT; i += 256) row[i] = h[i];
        return;
    }

    // ---- LSTM GEMM ----
    const int lb = blockIdx.x - nT;
    const int rel = (lb >= nblk0);
    const int nb = (rel ? (lb - nblk0) : lb) * 32;
    const float* x = rel ? x1 : x0;
    const float* bias = rel ? b1 : b0;
    unsigned short* msg = rel ? msg1 : msg0;
    const int N = rel ? N1 : N0;
    const unsigned short* wf = wfrag + (size_t)rel * 6144 * 8;

    {
        int r = tid >> 3;
        int c0 = (tid & 7) * 16;
        int n = nb + r;
        unsigned short* dstp = xs + r * XPAD + c0;
        if (n < N) {
            const float4* srcp = (const float4*)(x + (size_t)n * CCH + c0);
#pragma unroll
            for (int qq = 0; qq < 4; qq++) {
                float4 v = srcp[qq];
                unsigned u0 = (unsigned)f2bf(v.x) | ((unsigned)f2bf(v.y) << 16);
                unsigned u1 = (unsigned)f2bf(v.z) | ((unsigned)f2bf(v.w) << 16);
                *(uint2*)(dstp + qq * 4) = make_uint2(u0, u1);
            }
        } else {
#pragma unroll
            for (int qq = 0; qq < 4; qq++) *(uint2*)(dstp + qq * 4) = make_uint2(0u, 0u);
        }
    }
    __syncthreads();

    const int w = tid >> 6;
    const int l = tid & 63;
    const int ctb2 = w * 2;             // 2 col-tiles per wave
    const int q = l >> 4;
    const int m16 = l & 15;

    floatx4 acc[3][2][2];               // [gate][ct][mt]
#pragma unroll
    for (int g = 0; g < 3; g++)
#pragma unroll
        for (int c = 0; c < 2; c++)
#pragma unroll
            for (int mt = 0; mt < 2; mt++) acc[g][c][mt] = (floatx4){0.f, 0.f, 0.f, 0.f};

    const unsigned short* arow0 = xs + m16 * XPAD + q * 8;
    const unsigned short* arow1 = xs + (16 + m16) * XPAD + q * 8;
#pragma unroll
    for (int kc = 0; kc < 4; kc++) {
        short8 af0 = *(const short8*)(arow0 + kc * 32);
        short8 af1 = *(const short8*)(arow1 + kc * 32);
#pragma unroll
        for (int g = 0; g < 3; g++)
#pragma unroll
            for (int c = 0; c < 2; c++) {
                const unsigned short* bp = wf + ((((size_t)g * 8 + (ctb2 + c)) * 4 + kc) * 64 + l) * 8;
                short8 bv = *(const short8*)bp;
                acc[g][c][0] = __builtin_amdgcn_mfma_f32_16x16x32_bf16(af0, bv, acc[g][c][0], 0, 0, 0);
                acc[g][c][1] = __builtin_amdgcn_mfma_f32_16x16x32_bf16(af1, bv, acc[g][c][1], 0, 0, 0);
            }
    }

#pragma unroll
    for (int c = 0; c < 2; c++) {
        const int col = (ctb2 + c) * 16 + m16;
        const float bi = bias[col], bg = bias[256 + col], bo = bias[384 + col];
#pragma unroll
        for (int mt = 0; mt < 2; mt++)
#pragma unroll
            for (int r = 0; r < 4; r++) {
                const int node = nb + mt * 16 + q * 4 + r;
                if (node < N) {
                    float iv = sigmoidf_(acc[0][c][mt][r] + bi);
                    float gv = tanh_fast(acc[1][c][mt][r] + bg);
                    float ov = sigmoidf_(acc[2][c][mt][r] + bo);
                    msg[(size_t)node * CCH + col] = f2bf(ov * tanh_fast(iv * gv));
                }
            }
    }
}

// Pass 2: per-bucket exclusive scan over tiles (in place), bucket totals out.
__global__ __launch_bounds__(256) void colscan_kernel(
    int* __restrict__ H, int* __restrict__ btot, int nT, int NBKT)
{
    __shared__ int s[256];
    __shared__ int carry;
    const int g = blockIdx.x;
    const int tid = threadIdx.x;
    if (tid == 0) carry = 0;
    __syncthreads();
    for (int base = 0; base < nT; base += 256) {
        int b = base + tid;
        int v = (b < nT) ? H[(size_t)b * NBKT + g] : 0;
        s[tid] = v;
        __syncthreads();
#pragma unroll
        for (int off = 1; off < 256; off <<= 1) {
            int t = (tid >= off) ? s[tid - off] : 0;
            __syncthreads();
            s[tid] += t;
            __syncthreads();
        }
        if (b < nT) H[(size_t)b * NBKT + g] = s[tid] - v + carry;
        __syncthreads();
        if (tid == 255) carry += s[255];
        __syncthreads();
    }
    if (tid == 0) btot[g] = carry;
}

// Pass 3: re-read edges; LDS cursors = g*SLOT + H[tile][g]; write packed (dst&255)<<24|src.
__global__ __launch_bounds__(256) void tile_scatter_kernel(
    const int* __restrict__ src0, const int* __restrict__ dst0,
    const int* __restrict__ src1, const int* __restrict__ dst1,
    const int* __restrict__ H,
    unsigned* __restrict__ packed, int E0, int E1, int nbkt0, int NBKT)
{
    __shared__ int cur[MAXBKT];
    const int tid = threadIdx.x;
    const int* row = H + (size_t)blockIdx.x * NBKT;
    for (int i = tid; i < NBKT; i += 256) cur[i] = i * SLOT + row[i];
    __syncthreads();
    const long long Etot = (long long)E0 + E1;
    const long long base = (long long)blockIdx.x * TK;
    for (int i = tid; i < TK; i += 256) {
        long long e = base + i;
        if (e >= Etot) break;
        int s, g, k;
        if (e < E0) { int d = dst0[e]; s = src0[e]; g = d >> 8; k = d & 255; }
        else { long long ee = e - E0; int d = dst1[ee]; s = src1[ee]; g = nbkt0 + (d >> 8); k = d & 255; }
        int pos = atomicAdd(&cur[g], 1);
        packed[pos] = ((unsigned)k << 24) | (unsigned)s;
    }
}

// Pass 4: one block per bucket; in-LDS counting sort by 8-bit key; emit deg/offs.
__global__ __launch_bounds__(256) void fine_sort_kernel(
    unsigned* __restrict__ packed, const int* __restrict__ btot,
    int* __restrict__ offs0, int* __restrict__ deg0,
    int* __restrict__ offs1, int* __restrict__ deg1,
    int N0, int N1, int nbkt0)
{
    __shared__ unsigned pin[FCAP];
    __shared__ int sout[FCAP];
    __shared__ int hist[256], scn[256], cur[256];
    const int g = blockIdx.x;
    const int tid = threadIdx.x;
    const int base = g * SLOT;
    const int cnt = min(btot[g], FCAP);

    for (int i = tid; i < cnt; i += 256) pin[i] = packed[base + i];
    hist[tid] = 0;
    __syncthreads();
    for (int i = tid; i < cnt; i += 256) atomicAdd(&hist[pin[i] >> 24], 1);
    __syncthreads();
    int v = hist[tid];
    scn[tid] = v;
    __syncthreads();
#pragma unroll
    for (int off = 1; off < 256; off <<= 1) {
        int t = (tid >= off) ? scn[tid - off] : 0;
        __syncthreads();
        scn[tid] += t;
        __syncthreads();
    }
    int excl = scn[tid] - v;
    cur[tid] = excl;
    {
        const int rel = (g >= nbkt0);
        const int lb = rel ? g - nbkt0 : g;
        const int n = lb * 256 + tid;
        const int N = rel ? N1 : N0;
        if (n < N) {
            if (rel) { offs1[n] = base + excl; deg1[n] = v; }
            else     { offs0[n] = base + excl; deg0[n] = v; }
        }
    }
    __syncthreads();
    for (int i = tid; i < cnt; i += 256) {
        unsigned p = pin[i];
        int pos = atomicAdd(&cur[p >> 24], 1);
        sout[pos] = (int)(p & 0x00FFFFFFu);
    }
    __syncthreads();
    int* op = (int*)packed;
    for (int i = tid; i < cnt; i += 256) op[base + i] = sout[i];
}

// ---------------- fused gather + linear + relu ----------------
// 512 threads = 8 waves. XCD-split: blocks with (blockIdx&7)<4 -> rel0, else rel1
// (round-robin dispatch heuristic; correctness independent of mapping).
// Phase 1: stage x (all threads) + gather (wave w -> nodes 4w..4w+3, 2ch/lane).
// Phase 2: MFMA, wave w = col-tile w, both m-tiles.
__global__ __launch_bounds__(512) void gather_linear_kernel(
    const float* __restrict__ xd0, const float* __restrict__ xd1,
    const unsigned short* __restrict__ msg0, const unsigned short* __restrict__ msg1,
    const int* __restrict__ csr,
    const int* __restrict__ offs0, const int* __restrict__ offs1,
    const int* __restrict__ deg0, const int* __restrict__ deg1,
    const unsigned short* __restrict__ wfrag,
    const float* __restrict__ bl0, const float* __restrict__ bl1,
    float* __restrict__ out0, float* __restrict__ out1,
    int P0, int P1, int N0, int N1)
{
    __shared__ unsigned short s[32 * APAD];
    const int tid = threadIdx.x;
    const int grp = blockIdx.x >> 3;
    const int sub = blockIdx.x & 7;
    const int rel = (sub >> 2) & 1;
    const int lb = grp * 4 + (sub & 3);
    const int P = rel ? P1 : P0;
    if (lb >= P) return;
    const int nb = lb * 32;
    const float* xd = rel ? xd1 : xd0;
    const unsigned short* msg = rel ? msg1 : msg0;
    const int* offs = rel ? offs1 : offs0;
    const int* deg = rel ? deg1 : deg0;
    const float* bl = rel ? bl1 : bl0;
    float* outp = rel ? out1 : out0;
    const int N = rel ? N1 : N0;
    const unsigned short* wf = wfrag + (size_t)rel * 4096 * 8;

    {   // stage x_dst (bf16) : 512 threads, 16/row, 8 floats each
        int r = tid >> 4;
        int c0 = (tid & 15) * 8;
        int n = nb + r;
        unsigned short* drow = s + r * APAD + c0;
        if (n < N) {
            const float4* srcp = (const float4*)(xd + (size_t)n * CCH + c0);
            float4 v0 = srcp[0], v1 = srcp[1];
            uint4 u;
            u.x = (unsigned)f2bf(v0.x) | ((unsigned)f2bf(v0.y) << 16);
            u.y = (unsigned)f2bf(v0.z) | ((unsigned)f2bf(v0.w) << 16);
            u.z = (unsigned)f2bf(v1.x) | ((unsigned)f2bf(v1.y) << 16);
            u.w = (unsigned)f2bf(v1.z) | ((unsigned)f2bf(v1.w) << 16);
            *(uint4*)drow = u;
        } else {
            *(uint4*)drow = make_uint4(0u, 0u, 0u, 0u);
        }
    }
    {   // gather: wave w -> nodes 4w..4w+3
        const int w = tid >> 6;
        const int l = tid & 63;
        const unsigned short* mb = msg + l * 2;
#pragma unroll
        for (int m = 0; m < 4; m++) {
            const int nloc = w * 4 + m;
            const int n = nb + nloc;
            float ax = 0.f, ay = 0.f;
            if (n < N) {
                const int start = offs[n];
                const int cnt = deg[n];
                const int* ce = csr + start;
                int j = 0;
                for (; j + 8 <= cnt; j += 8) {
                    int s0 = ce[j], s1 = ce[j + 1], s2 = ce[j + 2], s3 = ce[j + 3];
                    int s4 = ce[j + 4], s5 = ce[j + 5], s6 = ce[j + 6], s7 = ce[j + 7];
                    unsigned u0 = *(const unsigned*)(mb + (size_t)s0 * CCH);
                    unsigned u1 = *(const unsigned*)(mb + (size_t)s1 * CCH);
                    unsigned u2 = *(const unsigned*)(mb + (size_t)s2 * CCH);
                    unsigned u3 = *(const unsigned*)(mb + (size_t)s3 * CCH);
                    unsigned u4 = *(const unsigned*)(mb + (size_t)s4 * CCH);
                    unsigned u5 = *(const unsigned*)(mb + (size_t)s5 * CCH);
                    unsigned u6 = *(const unsigned*)(mb + (size_t)s6 * CCH);
                    unsigned u7 = *(const unsigned*)(mb + (size_t)s7 * CCH);
                    ax += bf2f((unsigned short)u0) + bf2f((unsigned short)u1)
                        + bf2f((unsigned short)u2) + bf2f((unsigned short)u3)
                        + bf2f((unsigned short)u4) + bf2f((unsigned short)u5)
                        + bf2f((unsigned short)u6) + bf2f((unsigned short)u7);
                    ay += bf2f((unsigned short)(u0 >> 16)) + bf2f((unsigned short)(u1 >> 16))
                        + bf2f((unsigned short)(u2 >> 16)) + bf2f((unsigned short)(u3 >> 16))
                        + bf2f((unsigned short)(u4 >> 16)) + bf2f((unsigned short)(u5 >> 16))
                        + bf2f((unsigned short)(u6 >> 16)) + bf2f((unsigned short)(u7 >> 16));
                }
                for (; j + 4 <= cnt; j += 4) {
                    int s0 = ce[j], s1 = ce[j + 1], s2 = ce[j + 2], s3 = ce[j + 3];
                    unsigned u0 = *(const unsigned*)(mb + (size_t)s0 * CCH);
                    unsigned u1 = *(const unsigned*)(mb + (size_t)s1 * CCH);
                    unsigned u2 = *(const unsigned*)(mb + (size_t)s2 * CCH);
                    unsigned u3 = *(const unsigned*)(mb + (size_t)s3 * CCH);
                    ax += bf2f((unsigned short)u0) + bf2f((unsigned short)u1)
                        + bf2f((unsigned short)u2) + bf2f((unsigned short)u3);
                    ay += bf2f((unsigned short)(u0 >> 16)) + bf2f((unsigned short)(u1 >> 16))
                        + bf2f((unsigned short)(u2 >> 16)) + bf2f((unsigned short)(u3 >> 16));
                }
                for (; j < cnt; j++) {
                    unsigned u0 = *(const unsigned*)(mb + (size_t)ce[j] * CCH);
                    ax += bf2f((unsigned short)u0);
                    ay += bf2f((unsigned short)(u0 >> 16));
                }
            }
            unsigned o = (unsigned)f2bf(ax) | ((unsigned)f2bf(ay) << 16);
            *(unsigned*)(s + nloc * APAD + CCH + l * 2) = o;
        }
    }
    __syncthreads();

    // MFMA: wave w = col-tile w; both m-tiles
    const int w = tid >> 6;
    const int l = tid & 63;
    const int q = l >> 4;
    const int m16 = l & 15;

    floatx4 acc[2];
    acc[0] = (floatx4){0.f, 0.f, 0.f, 0.f};
    acc[1] = (floatx4){0.f, 0.f, 0.f, 0.f};

    const unsigned short* arow0 = s + m16 * APAD + q * 8;
    const unsigned short* arow1 = s + (16 + m16) * APAD + q * 8;
#pragma unroll
    for (int kc = 0; kc < 8; kc++) {
        short8 af0 = *(const short8*)(arow0 + kc * 32);
        short8 af1 = *(const short8*)(arow1 + kc * 32);
        const unsigned short* bp = wf + ((((size_t)w) * 8 + kc) * 64 + l) * 8;
        short8 bv = *(const short8*)bp;
        acc[0] = __builtin_amdgcn_mfma_f32_16x16x32_bf16(af0, bv, acc[0], 0, 0, 0);
        acc[1] = __builtin_amdgcn_mfma_f32_16x16x32_bf16(af1, bv, acc[1], 0, 0, 0);
    }

    const int col = w * 16 + m16;
    const float bv = bl[col];
#pragma unroll
    for (int mt = 0; mt < 2; mt++)
#pragma unroll
        for (int r = 0; r < 4; r++) {
            const int node = nb + mt * 16 + q * 4 + r;
            if (node < N) outp[(size_t)node * CCH + col] = fmaxf(acc[mt][r] + bv, 0.0f);
        }
}

extern "C" void kernel_launch(void* const* d_in, const int* in_sizes, int n_in,
                              void* d_out, int out_size, void* d_ws, size_t ws_size,
                              hipStream_t stream) {
    const float* x_a      = (const float*)d_in[0];
    const float* x_b      = (const float*)d_in[1];
    const int*   e_ab     = (const int*)d_in[2];
    const int*   e_ba     = (const int*)d_in[3];
    const float* W_ih_ab  = (const float*)d_in[4];
    const float* b_ab     = (const float*)d_in[5];
    const float* W_lin_ab = (const float*)d_in[6];
    const float* b_lin_ab = (const float*)d_in[7];
    const float* W_ih_ba  = (const float*)d_in[8];
    const float* b_ba     = (const float*)d_in[9];
    const float* W_lin_ba = (const float*)d_in[10];
    const float* b_lin_ba = (const float*)d_in[11];

    const int NA = in_sizes[0] / CCH;
    const int NB = in_sizes[1] / CCH;
    const int E0 = in_sizes[2] / 2;   // a->b (dst in B)
    const int E1 = in_sizes[3] / 2;   // b->a (dst in A)

    float* out = (float*)d_out;
    char* ws = (char*)d_ws;
    size_t off = 0;
    auto alloc = [&](size_t bytes) { char* p = ws + off; off += (bytes + 255) & ~(size_t)255; return p; };

    unsigned short* wfrag_ih  = (unsigned short*)alloc(12288 * 8 * 2);
    unsigned short* wfrag_lin = (unsigned short*)alloc(8192 * 8 * 2);
    unsigned short* msg_a     = (unsigned short*)alloc((size_t)NA * CCH * 2);
    unsigned short* msg_b     = (unsigned short*)alloc((size_t)NB * CCH * 2);

    const int nbkt0 = (NB + 255) / 256;   // rel0 coarse buckets (dst in B)
    const int nbkt1 = (NA + 255) / 256;   // rel1 (dst in A)
    const int NBKT = nbkt0 + nbkt1;
    const long long Etot = (long long)E0 + E1;
    const int nT = (int)((Etot + TK - 1) / TK);

    int* H      = (int*)alloc((size_t)nT * NBKT * 4);
    int* btot   = (int*)alloc((size_t)NBKT * 4);
    int* offs_b = (int*)alloc((size_t)NB * 4);
    int* offs_a = (int*)alloc((size_t)NA * 4);
    int* deg_b  = (int*)alloc((size_t)NB * 4);
    int* deg_a  = (int*)alloc((size_t)NA * 4);
    unsigned* packed = (unsigned*)alloc((size_t)NBKT * SLOT * 4);  // fixed slots; becomes csr

    const int nblkA = (NA + 31) / 32;
    const int nblkB = (NB + 31) / 32;

    prep_weights_kernel<<<80, 256, 0, stream>>>(
        W_ih_ab, W_ih_ba, W_lin_ab, W_lin_ba, wfrag_ih, wfrag_lin);

    // fused: blocks [0,nT) = edge histogram; rest = LSTM GEMM (rel0: a->b src A; rel1: b->a src B)
    lstm_hist_kernel<<<nT + nblkA + nblkB, 256, 0, stream>>>(
        x_a, x_b, wfrag_ih, b_ab, b_ba, msg_a, msg_b, NA, NB, nblkA,
        e_ab + E0, e_ba + E1, H, E0, E1, nbkt0, NBKT, nT);

    colscan_kernel<<<NBKT, 256, 0, stream>>>(H, btot, nT, NBKT);
    tile_scatter_kernel<<<nT, 256, 0, stream>>>(
        e_ab, e_ab + E0, e_ba, e_ba + E1, H, packed, E0, E1, nbkt0, NBKT);
    fine_sort_kernel<<<NBKT, 256, 0, stream>>>(
        packed, btot, offs_b, deg_b, offs_a, deg_a, NB, NA, nbkt0);

    // fused gather + linear; rel0 -> out_b (index 1), rel1 -> out_a (index 0)
    const int Pmax = (nblkB > nblkA) ? nblkB : nblkA;
    const int G = ((Pmax + 3) / 4) * 8;
    gather_linear_kernel<<<G, 512, 0, stream>>>(
        x_b, x_a, msg_a, msg_b, (const int*)packed,
        offs_b, offs_a, deg_b, deg_a, wfrag_lin, b_lin_ab, b_lin_ba,
        out + (size_t)NA * CCH, out, nblkB, nblkA, NB, NA);
}

// Round 8
// 270.453 us; speedup vs baseline: 3.2065x; 1.0345x over previous
//
#include <hip/hip_runtime.h>
#include <cstdint>
#include <cstddef>

#define CCH 128
#define TK 8192      // edges per tile in CSR build
#define FCAP 8192    // fine-sort bucket capacity == fixed slot size
#define SLOT 8192    // fixed packed-array slot per coarse bucket
#define MAXBKT 512   // max coarse buckets (392 actual)
#define XPAD 136     // 128 + 8 bf16 pad
#define APAD 264     // 256 + 8 pad

typedef __attribute__((ext_vector_type(8))) short short8;
typedef __attribute__((ext_vector_type(4))) float floatx4;

__device__ __forceinline__ unsigned short f2bf(float f) {
    unsigned u = __builtin_bit_cast(unsigned, f);
    u += 0x7fffu + ((u >> 16) & 1u);   // RNE
    return (unsigned short)(u >> 16);
}
__device__ __forceinline__ float bf2f(unsigned short h) {
    unsigned u = ((unsigned)h) << 16;
    return __builtin_bit_cast(float, u);
}
__device__ __forceinline__ float sigmoidf_(float x) { return 1.0f / (1.0f + __expf(-x)); }
__device__ __forceinline__ float tanh_fast(float x) {
    x = fminf(fmaxf(x, -10.0f), 10.0f);
    float e = __expf(2.0f * x);
    return (e - 1.0f) / (e + 1.0f);
}

// ---------------- merged weight prep: fragment-ready bf16 ----------------
__global__ __launch_bounds__(256) void prep_weights_kernel(
    const float* __restrict__ Wih0, const float* __restrict__ Wih1,
    const float* __restrict__ Wlin0, const float* __restrict__ Wlin1,
    unsigned short* __restrict__ frag_ih, unsigned short* __restrict__ frag_lin)
{
    int t = blockIdx.x * 256 + threadIdx.x;
    if (t < 12288) {
        int l  = t & 63;
        int kc = (t >> 6) & 3;
        int ct = (t >> 8) & 7;
        int g  = (t >> 11) % 3;
        int rel = t / 6144;
        int gb = (g == 0) ? 0 : (g == 1 ? 256 : 384);
        const float* W = rel ? Wih1 : Wih0;
        int n  = gb + ct * 16 + (l & 15);
        int kb = kc * 32 + (l >> 4) * 8;
        unsigned short* o = frag_ih + (size_t)t * 8;
#pragma unroll
        for (int j = 0; j < 8; j++) o[j] = f2bf(W[(size_t)n * CCH + kb + j]);
    } else {
        int t2 = t - 12288;
        if (t2 >= 8192) return;
        int l  = t2 & 63;
        int kc = (t2 >> 6) & 7;
        int ct = (t2 >> 9) & 7;
        int rel = t2 >> 12;
        const float* W = rel ? Wlin1 : Wlin0;
        int n  = ct * 16 + (l & 15);
        int kb = kc * 32 + (l >> 4) * 8;
        unsigned short* o = frag_lin + (size_t)t2 * 8;
#pragma unroll
        for (int j = 0; j < 8; j++) o[j] = f2bf(W[(size_t)n * 256 + kb + j]);
    }
}

// ---------------- LSTM message via MFMA + fused edge histogram ----------------
__global__ __launch_bounds__(256) void lstm_hist_kernel(
    const float* __restrict__ x0, const float* __restrict__ x1,
    const unsigned short* __restrict__ wfrag,
    const float* __restrict__ b0, const float* __restrict__ b1,
    unsigned short* __restrict__ msg0, unsigned short* __restrict__ msg1,
    int N0, int N1, int nblk0,
    const int* __restrict__ dstE0, const int* __restrict__ dstE1,
    int* __restrict__ H, int E0, int E1, int nbkt0, int NBKT, int nT)
{
    __shared__ unsigned short xs[32 * XPAD];
    __shared__ int h[MAXBKT];
    const int tid = threadIdx.x;

    if (blockIdx.x < nT) {   // ---- histogram tile ----
        for (int i = tid; i < NBKT; i += 256) h[i] = 0;
        __syncthreads();
        const long long Etot = (long long)E0 + E1;
        const long long base = (long long)blockIdx.x * TK;
        for (int i = tid; i < TK; i += 256) {
            long long e = base + i;
            if (e >= Etot) break;
            int g;
            if (e < E0) g = dstE0[e] >> 8;
            else        g = nbkt0 + (dstE1[e - E0] >> 8);
            atomicAdd(&h[g], 1);
        }
        __syncthreads();
        int* row = H + (size_t)blockIdx.x * NBKT;
        for (int i = tid; i < NBKT; i += 256) row[i] = h[i];
        return;
    }

    // ---- LSTM GEMM ----
    const int lb = blockIdx.x - nT;
    const int rel = (lb >= nblk0);
    const int nb = (rel ? (lb - nblk0) : lb) * 32;
    const float* x = rel ? x1 : x0;
    const float* bias = rel ? b1 : b0;
    unsigned short* msg = rel ? msg1 : msg0;
    const int N = rel ? N1 : N0;
    const unsigned short* wf = wfrag + (size_t)rel * 6144 * 8;

    {
        int r = tid >> 3;
        int c0 = (tid & 7) * 16;
        int n = nb + r;
        unsigned short* dstp = xs + r * XPAD + c0;
        if (n < N) {
            const float4* srcp = (const float4*)(x + (size_t)n * CCH + c0);
#pragma unroll
            for (int qq = 0; qq < 4; qq++) {
                float4 v = srcp[qq];
                unsigned u0 = (unsigned)f2bf(v.x) | ((unsigned)f2bf(v.y) << 16);
                unsigned u1 = (unsigned)f2bf(v.z) | ((unsigned)f2bf(v.w) << 16);
                *(uint2*)(dstp + qq * 4) = make_uint2(u0, u1);
            }
        } else {
#pragma unroll
            for (int qq = 0; qq < 4; qq++) *(uint2*)(dstp + qq * 4) = make_uint2(0u, 0u);
        }
    }
    __syncthreads();

    const int w = tid >> 6;
    const int l = tid & 63;
    const int ctb2 = w * 2;             // 2 col-tiles per wave
    const int q = l >> 4;
    const int m16 = l & 15;

    floatx4 acc[3][2][2];               // [gate][ct][mt]
#pragma unroll
    for (int g = 0; g < 3; g++)
#pragma unroll
        for (int c = 0; c < 2; c++)
#pragma unroll
            for (int mt = 0; mt < 2; mt++) acc[g][c][mt] = (floatx4){0.f, 0.f, 0.f, 0.f};

    const unsigned short* arow0 = xs + m16 * XPAD + q * 8;
    const unsigned short* arow1 = xs + (16 + m16) * XPAD + q * 8;
#pragma unroll
    for (int kc = 0; kc < 4; kc++) {
        short8 af0 = *(const short8*)(arow0 + kc * 32);
        short8 af1 = *(const short8*)(arow1 + kc * 32);
#pragma unroll
        for (int g = 0; g < 3; g++)
#pragma unroll
            for (int c = 0; c < 2; c++) {
                const unsigned short* bp = wf + ((((size_t)g * 8 + (ctb2 + c)) * 4 + kc) * 64 + l) * 8;
                short8 bv = *(const short8*)bp;
                acc[g][c][0] = __builtin_amdgcn_mfma_f32_16x16x32_bf16(af0, bv, acc[g][c][0], 0, 0, 0);
                acc[g][c][1] = __builtin_amdgcn_mfma_f32_16x16x32_bf16(af1, bv, acc[g][c][1], 0, 0, 0);
            }
    }

#pragma unroll
    for (int c = 0; c < 2; c++) {
        const int col = (ctb2 + c) * 16 + m16;
        const float bi = bias[col], bg = bias[256 + col], bo = bias[384 + col];
#pragma unroll
        for (int mt = 0; mt < 2; mt++)
#pragma unroll
            for (int r = 0; r < 4; r++) {
                const int node = nb + mt * 16 + q * 4 + r;
                if (node < N) {
                    float iv = sigmoidf_(acc[0][c][mt][r] + bi);
                    float gv = tanh_fast(acc[1][c][mt][r] + bg);
                    float ov = sigmoidf_(acc[2][c][mt][r] + bo);
                    msg[(size_t)node * CCH + col] = f2bf(ov * tanh_fast(iv * gv));
                }
            }
    }
}

// Pass 2: per-bucket exclusive scan over tiles (in place), bucket totals out.
__global__ __launch_bounds__(256) void colscan_kernel(
    int* __restrict__ H, int* __restrict__ btot, int nT, int NBKT)
{
    __shared__ int s[256];
    __shared__ int carry;
    const int g = blockIdx.x;
    const int tid = threadIdx.x;
    if (tid == 0) carry = 0;
    __syncthreads();
    for (int base = 0; base < nT; base += 256) {
        int b = base + tid;
        int v = (b < nT) ? H[(size_t)b * NBKT + g] : 0;
        s[tid] = v;
        __syncthreads();
#pragma unroll
        for (int off = 1; off < 256; off <<= 1) {
            int t = (tid >= off) ? s[tid - off] : 0;
            __syncthreads();
            s[tid] += t;
            __syncthreads();
        }
        if (b < nT) H[(size_t)b * NBKT + g] = s[tid] - v + carry;
        __syncthreads();
        if (tid == 255) carry += s[255];
        __syncthreads();
    }
    if (tid == 0) btot[g] = carry;
}

// Pass 3: re-read edges; LDS cursors = g*SLOT + H[tile][g]; write packed (dst&255)<<24|src.
__global__ __launch_bounds__(256) void tile_scatter_kernel(
    const int* __restrict__ src0, const int* __restrict__ dst0,
    const int* __restrict__ src1, const int* __restrict__ dst1,
    const int* __restrict__ H,
    unsigned* __restrict__ packed, int E0, int E1, int nbkt0, int NBKT)
{
    __shared__ int cur[MAXBKT];
    const int tid = threadIdx.x;
    const int* row = H + (size_t)blockIdx.x * NBKT;
    for (int i = tid; i < NBKT; i += 256) cur[i] = i * SLOT + row[i];
    __syncthreads();
    const long long Etot = (long long)E0 + E1;
    const long long base = (long long)blockIdx.x * TK;
    for (int i = tid; i < TK; i += 256) {
        long long e = base + i;
        if (e >= Etot) break;
        int s, g, k;
        if (e < E0) { int d = dst0[e]; s = src0[e]; g = d >> 8; k = d & 255; }
        else { long long ee = e - E0; int d = dst1[ee]; s = src1[ee]; g = nbkt0 + (d >> 8); k = d & 255; }
        int pos = atomicAdd(&cur[g], 1);
        packed[pos] = ((unsigned)k << 24) | (unsigned)s;
    }
}

// Pass 4: one block per bucket; in-LDS counting sort by 8-bit key; emit deg/offs.
__global__ __launch_bounds__(256) void fine_sort_kernel(
    unsigned* __restrict__ packed, const int* __restrict__ btot,
    int* __restrict__ offs0, int* __restrict__ deg0,
    int* __restrict__ offs1, int* __restrict__ deg1,
    int N0, int N1, int nbkt0)
{
    __shared__ unsigned pin[FCAP];
    __shared__ int sout[FCAP];
    __shared__ int hist[256], scn[256], cur[256];
    const int g = blockIdx.x;
    const int tid = threadIdx.x;
    const int base = g * SLOT;
    const int cnt = min(btot[g], FCAP);

    for (int i = tid; i < cnt; i += 256) pin[i] = packed[base + i];
    hist[tid] = 0;
    __syncthreads();
    for (int i = tid; i < cnt; i += 256) atomicAdd(&hist[pin[i] >> 24], 1);
    __syncthreads();
    int v = hist[tid];
    scn[tid] = v;
    __syncthreads();
#pragma unroll
    for (int off = 1; off < 256; off <<= 1) {
        int t = (tid >= off) ? scn[tid - off] : 0;
        __syncthreads();
        scn[tid] += t;
        __syncthreads();
    }
    int excl = scn[tid] - v;
    cur[tid] = excl;
    {
        const int rel = (g >= nbkt0);
        const int lb = rel ? g - nbkt0 : g;
        const int n = lb * 256 + tid;
        const int N = rel ? N1 : N0;
        if (n < N) {
            if (rel) { offs1[n] = base + excl; deg1[n] = v; }
            else     { offs0[n] = base + excl; deg0[n] = v; }
        }
    }
    __syncthreads();
    for (int i = tid; i < cnt; i += 256) {
        unsigned p = pin[i];
        int pos = atomicAdd(&cur[p >> 24], 1);
        sout[pos] = (int)(p & 0x00FFFFFFu);
    }
    __syncthreads();
    int* op = (int*)packed;
    for (int i = tid; i < cnt; i += 256) op[base + i] = sout[i];
}

// ---------------- fused gather + linear + relu ----------------
// 512 threads = 8 waves. XCD-split: (blockIdx&7)<4 -> rel0, else rel1.
// Gather: wave w, lane-group g=l>>4 owns node 4w+g; lane c=l&15 loads 16 B
// (8 channels) of an edge-row -> one wave-instr covers 4 edge-rows (1 KB).
// Each lane accumulates its 8 channels in registers; no cross-lane reduce.
// Phase 2: MFMA, wave w = col-tile w, both m-tiles.
__global__ __launch_bounds__(512) void gather_linear_kernel(
    const float* __restrict__ xd0, const float* __restrict__ xd1,
    const unsigned short* __restrict__ msg0, const unsigned short* __restrict__ msg1,
    const int* __restrict__ csr,
    const int* __restrict__ offs0, const int* __restrict__ offs1,
    const int* __restrict__ deg0, const int* __restrict__ deg1,
    const unsigned short* __restrict__ wfrag,
    const float* __restrict__ bl0, const float* __restrict__ bl1,
    float* __restrict__ out0, float* __restrict__ out1,
    int P0, int P1, int N0, int N1)
{
    __shared__ unsigned short s[32 * APAD];
    const int tid = threadIdx.x;
    const int grp = blockIdx.x >> 3;
    const int sub = blockIdx.x & 7;
    const int rel = (sub >> 2) & 1;
    const int lb = grp * 4 + (sub & 3);
    const int P = rel ? P1 : P0;
    if (lb >= P) return;
    const int nb = lb * 32;
    const float* xd = rel ? xd1 : xd0;
    const unsigned short* msg = rel ? msg1 : msg0;
    const int* offs = rel ? offs1 : offs0;
    const int* deg = rel ? deg1 : deg0;
    const float* bl = rel ? bl1 : bl0;
    float* outp = rel ? out1 : out0;
    const int N = rel ? N1 : N0;
    const unsigned short* wf = wfrag + (size_t)rel * 4096 * 8;

    {   // stage x_dst (bf16) : 512 threads, 16/row, 8 floats each
        int r = tid >> 4;
        int c0 = (tid & 15) * 8;
        int n = nb + r;
        unsigned short* drow = s + r * APAD + c0;
        if (n < N) {
            const float4* srcp = (const float4*)(xd + (size_t)n * CCH + c0);
            float4 v0 = srcp[0], v1 = srcp[1];
            uint4 u;
            u.x = (unsigned)f2bf(v0.x) | ((unsigned)f2bf(v0.y) << 16);
            u.y = (unsigned)f2bf(v0.z) | ((unsigned)f2bf(v0.w) << 16);
            u.z = (unsigned)f2bf(v1.x) | ((unsigned)f2bf(v1.y) << 16);
            u.w = (unsigned)f2bf(v1.z) | ((unsigned)f2bf(v1.w) << 16);
            *(uint4*)drow = u;
        } else {
            *(uint4*)drow = make_uint4(0u, 0u, 0u, 0u);
        }
    }
    {   // gather: lane-group per node, 16 B/lane
        const int w = tid >> 6;
        const int l = tid & 63;
        const int g = l >> 4;           // lane group -> node 4w+g
        const int c = l & 15;           // channels 8c..8c+7
        const int nloc = w * 4 + g;
        const int n = nb + nloc;
        float a0 = 0.f, a1 = 0.f, a2 = 0.f, a3 = 0.f;
        float a4 = 0.f, a5 = 0.f, a6 = 0.f, a7 = 0.f;
        if (n < N) {
            const int start = offs[n];
            const int cnt = deg[n];
            const int* ce = csr + start;
            const unsigned short* mb = msg + c * 8;
#define ACC8(U) { \
            a0 += bf2f((unsigned short)(U.x)); a1 += bf2f((unsigned short)((U.x) >> 16)); \
            a2 += bf2f((unsigned short)(U.y)); a3 += bf2f((unsigned short)((U.y) >> 16)); \
            a4 += bf2f((unsigned short)(U.z)); a5 += bf2f((unsigned short)((U.z) >> 16)); \
            a6 += bf2f((unsigned short)(U.w)); a7 += bf2f((unsigned short)((U.w) >> 16)); }
            int j = 0;
            for (; j + 4 <= cnt; j += 4) {
                int s0 = ce[j], s1 = ce[j + 1], s2 = ce[j + 2], s3 = ce[j + 3];
                uint4 u0 = *(const uint4*)(mb + (size_t)s0 * CCH);
                uint4 u1 = *(const uint4*)(mb + (size_t)s1 * CCH);
                uint4 u2 = *(const uint4*)(mb + (size_t)s2 * CCH);
                uint4 u3 = *(const uint4*)(mb + (size_t)s3 * CCH);
                ACC8(u0); ACC8(u1); ACC8(u2); ACC8(u3);
            }
            for (; j < cnt; j++) {
                uint4 u0 = *(const uint4*)(mb + (size_t)ce[j] * CCH);
                ACC8(u0);
            }
#undef ACC8
        }
        uint4 o;
        o.x = (unsigned)f2bf(a0) | ((unsigned)f2bf(a1) << 16);
        o.y = (unsigned)f2bf(a2) | ((unsigned)f2bf(a3) << 16);
        o.z = (unsigned)f2bf(a4) | ((unsigned)f2bf(a5) << 16);
        o.w = (unsigned)f2bf(a6) | ((unsigned)f2bf(a7) << 16);
        *(uint4*)(s + nloc * APAD + CCH + c * 8) = o;
    }
    __syncthreads();

    // MFMA: wave w = col-tile w; both m-tiles
    const int w = tid >> 6;
    const int l = tid & 63;
    const int q = l >> 4;
    const int m16 = l & 15;

    floatx4 acc[2];
    acc[0] = (floatx4){0.f, 0.f, 0.f, 0.f};
    acc[1] = (floatx4){0.f, 0.f, 0.f, 0.f};

    const unsigned short* arow0 = s + m16 * APAD + q * 8;
    const unsigned short* arow1 = s + (16 + m16) * APAD + q * 8;
#pragma unroll
    for (int kc = 0; kc < 8; kc++) {
        short8 af0 = *(const short8*)(arow0 + kc * 32);
        short8 af1 = *(const short8*)(arow1 + kc * 32);
        const unsigned short* bp = wf + ((((size_t)w) * 8 + kc) * 64 + l) * 8;
        short8 bv = *(const short8*)bp;
        acc[0] = __builtin_amdgcn_mfma_f32_16x16x32_bf16(af0, bv, acc[0], 0, 0, 0);
        acc[1] = __builtin_amdgcn_mfma_f32_16x16x32_bf16(af1, bv, acc[1], 0, 0, 0);
    }

    const int col = w * 16 + m16;
    const float bv = bl[col];
#pragma unroll
    for (int mt = 0; mt < 2; mt++)
#pragma unroll
        for (int r = 0; r < 4; r++) {
            const int node = nb + mt * 16 + q * 4 + r;
            if (node < N) outp[(size_t)node * CCH + col] = fmaxf(acc[mt][r] + bv, 0.0f);
        }
}

extern "C" void kernel_launch(void* const* d_in, const int* in_sizes, int n_in,
                              void* d_out, int out_size, void* d_ws, size_t ws_size,
                              hipStream_t stream) {
    const float* x_a      = (const float*)d_in[0];
    const float* x_b      = (const float*)d_in[1];
    const int*   e_ab     = (const int*)d_in[2];
    const int*   e_ba     = (const int*)d_in[3];
    const float* W_ih_ab  = (const float*)d_in[4];
    const float* b_ab     = (const float*)d_in[5];
    const float* W_lin_ab = (const float*)d_in[6];
    const float* b_lin_ab = (const float*)d_in[7];
    const float* W_ih_ba  = (const float*)d_in[8];
    const float* b_ba     = (const float*)d_in[9];
    const float* W_lin_ba = (const float*)d_in[10];
    const float* b_lin_ba = (const float*)d_in[11];

    const int NA = in_sizes[0] / CCH;
    const int NB = in_sizes[1] / CCH;
    const int E0 = in_sizes[2] / 2;   // a->b (dst in B)
    const int E1 = in_sizes[3] / 2;   // b->a (dst in A)

    float* out = (float*)d_out;
    char* ws = (char*)d_ws;
    size_t off = 0;
    auto alloc = [&](size_t bytes) { char* p = ws + off; off += (bytes + 255) & ~(size_t)255; return p; };

    unsigned short* wfrag_ih  = (unsigned short*)alloc(12288 * 8 * 2);
    unsigned short* wfrag_lin = (unsigned short*)alloc(8192 * 8 * 2);
    unsigned short* msg_a     = (unsigned short*)alloc((size_t)NA * CCH * 2);
    unsigned short* msg_b     = (unsigned short*)alloc((size_t)NB * CCH * 2);

    const int nbkt0 = (NB + 255) / 256;   // rel0 coarse buckets (dst in B)
    const int nbkt1 = (NA + 255) / 256;   // rel1 (dst in A)
    const int NBKT = nbkt0 + nbkt1;
    const long long Etot = (long long)E0 + E1;
    const int nT = (int)((Etot + TK - 1) / TK);

    int* H      = (int*)alloc((size_t)nT * NBKT * 4);
    int* btot   = (int*)alloc((size_t)NBKT * 4);
    int* offs_b = (int*)alloc((size_t)NB * 4);
    int* offs_a = (int*)alloc((size_t)NA * 4);
    int* deg_b  = (int*)alloc((size_t)NB * 4);
    int* deg_a  = (int*)alloc((size_t)NA * 4);
    unsigned* packed = (unsigned*)alloc((size_t)NBKT * SLOT * 4);  // fixed slots; becomes csr

    const int nblkA = (NA + 31) / 32;
    const int nblkB = (NB + 31) / 32;

    prep_weights_kernel<<<80, 256, 0, stream>>>(
        W_ih_ab, W_ih_ba, W_lin_ab, W_lin_ba, wfrag_ih, wfrag_lin);

    // fused: blocks [0,nT) = edge histogram; rest = LSTM GEMM (rel0: a->b src A; rel1: b->a src B)
    lstm_hist_kernel<<<nT + nblkA + nblkB, 256, 0, stream>>>(
        x_a, x_b, wfrag_ih, b_ab, b_ba, msg_a, msg_b, NA, NB, nblkA,
        e_ab + E0, e_ba + E1, H, E0, E1, nbkt0, NBKT, nT);

    colscan_kernel<<<NBKT, 256, 0, stream>>>(H, btot, nT, NBKT);
    tile_scatter_kernel<<<nT, 256, 0, stream>>>(
        e_ab, e_ab + E0, e_ba, e_ba + E1, H, packed, E0, E1, nbkt0, NBKT);
    fine_sort_kernel<<<NBKT, 256, 0, stream>>>(
        packed, btot, offs_b, deg_b, offs_a, deg_a, NB, NA, nbkt0);

    // fused gather + linear; rel0 -> out_b (index 1), rel1 -> out_a (index 0)
    const int Pmax = (nblkB > nblkA) ? nblkB : nblkA;
    const int G = ((Pmax + 3) / 4) * 8;
    gather_linear_kernel<<<G, 512, 0, stream>>>(
        x_b, x_a, msg_a, msg_b, (const int*)packed,
        offs_b, offs_a, deg_b, deg_a, wfrag_lin, b_lin_ab, b_lin_ba,
        out + (size_t)NA * CCH, out, nblkB, nblkA, NB, NA);
}